// Round 12
// baseline (394.502 us; speedup 1.0000x reference)
//
#include <hip/hip_runtime.h>
#include <math.h>

// R27: R26's fused-epilogue failed correctness for ONE reason: the counter
// zeroing block ran `if (tid<288) cnt[tid]=0` with 256 threads -> counters
// 256..287 (b=1, qt>=112) kept garbage -> those 32 tiles never (or early)
// closed -> outputs stayed memset-zero, absmax 7.9e-2 == |ref| there. The
// release/ACQ_REL-agent/acquire protocol itself worked (256 good tiles).
// Fix: strided zeroing loop covering all 288. Everything else identical to
// R26: 2 dispatches (qkvprep, attnout); attn main loop = R23 proven 32-key
// body; outcomp epilogue by the 16th finishing (h,which) wave per (qt,b).
#define BATCH 2
#define C 64
#define HH 48
#define WW 48
#define NTOK 2304
#define HEADS 8
#define KVSTRIDE 12

typedef unsigned short bf16_t;
typedef __attribute__((ext_vector_type(8))) short bf16x8;
typedef __attribute__((ext_vector_type(4))) short bf16x4;
typedef __attribute__((ext_vector_type(4))) float f32x4;

__device__ __forceinline__ bf16_t f2bf(float f) {
    unsigned int u = __float_as_uint(f);
    u = (u + 0x7fffu + ((u >> 16) & 1u)) >> 16;   // RNE
    return (bf16_t)u;
}
__device__ __forceinline__ unsigned pack2(float a, float b) {
    return (unsigned)f2bf(a) | ((unsigned)f2bf(b) << 16);
}
__device__ __forceinline__ float4 ld_bf4(const bf16_t* p) {
    uint2 v = *(const uint2*)p;
    float4 r;
    r.x = __uint_as_float(v.x << 16); r.y = __uint_as_float(v.x & 0xffff0000u);
    r.z = __uint_as_float(v.y << 16); r.w = __uint_as_float(v.y & 0xffff0000u);
    return r;
}

// Stage one token-row of X. strm 0: rgb transpose gather. strm 1: conv1x1+
// ReLU+bilinear x2 (half-pixel; clamp == jax edge renorm for 24->48).
__device__ __forceinline__ void stage_x_row(
    float* xrow, const float* rgb, const float* dep,
    const float* w_exp, const float* b_exp,
    int b, int n, int strm, int c0, int cstep)
{
    int wi = n / HH, hi = n % HH;
    if (strm == 0) {
        const float* base = rgb + (size_t)b * C * NTOK + (size_t)hi * WW + wi;
        for (int c = c0; c < 64; c += cstep)
            xrow[c] = base[(size_t)c * NTOK];
    } else {
        float cy = 0.5f * hi - 0.25f, cx = 0.5f * wi - 0.25f;
        float fy0 = floorf(cy), fx0 = floorf(cx);
        float fy = cy - fy0, fx = cx - fx0;
        int y0 = max((int)fy0, 0), x0 = max((int)fx0, 0);
        int y1 = min((int)fy0 + 1, 23), x1 = min((int)fx0 + 1, 23);
        const float* dp = dep + b * 576;
        float d00 = dp[y0*24 + x0], d01 = dp[y0*24 + x1];
        float d10 = dp[y1*24 + x0], d11 = dp[y1*24 + x1];
        for (int c = c0; c < 64; c += cstep) {
            float w = w_exp[c], bb = b_exp[c];
            float r00 = fmaxf(w*d00 + bb, 0.f), r01 = fmaxf(w*d01 + bb, 0.f);
            float r10 = fmaxf(w*d10 + bb, 0.f), r11 = fmaxf(w*d11 + bb, 0.f);
            xrow[c] = (1.f-fy)*((1.f-fx)*r00 + fx*r01) + fy*((1.f-fx)*r10 + fx*r11);
        }
    }
}

// ===========================================================================
// MAIN PATH: 2 dispatches (qkvprep, attnout).
// ===========================================================================

// qkvprep: grid(145, 4, 3). Blocks x<144: ONE GEMM per block — tile=x,
// z=y (b*2+strm), m=z-dim (0=Q 1=K 2=V); X gathered in-block (proven).
// Block (144, y, z<2): wprep task m=z, strip bx=y. Block (144, 0, 2):
// zero ALL 288 completion counters (strided; R26's bug was tid<288 with
// only 256 threads).
__global__ __launch_bounds__(256) void qkvprep_kernel(
    const float* __restrict__ rgb, const float* __restrict__ dep,
    const float* __restrict__ w_exp, const float* __restrict__ b_exp,
    const float* __restrict__ w_rq, const float* __restrict__ w_rk,
    const float* __restrict__ w_rv,
    const float* __restrict__ w_dq, const float* __restrict__ w_dk,
    const float* __restrict__ w_dv,
    const float* __restrict__ w_rp, const float* __restrict__ w_dp,
    const float* __restrict__ w_comp,
    const float* __restrict__ b_rp, const float* __restrict__ b_dp,
    const float* __restrict__ b_comp,
    bf16_t* __restrict__ Qb, bf16_t* __restrict__ Kb, bf16_t* __restrict__ VT,
    float* __restrict__ W1, float* __restrict__ W2, float* __restrict__ beff,
    unsigned* __restrict__ cnt)
{
    __shared__ float Xs[16][68];
    __shared__ float Ws[64][68];
    int bxid = blockIdx.x;
    int tid = threadIdx.x;
    int sr = tid >> 4, sc = (tid & 15) * 4;

    if (bxid < 144) {
        int tile = bxid;
        int z = blockIdx.y;              // b*2 + strm
        int m = blockIdx.z;              // 0=Q 1=K 2=V
        int b = z >> 1, strm = z & 1;
        int sb = strm*2 + b;
        const float* W = strm ? (m == 0 ? w_dq : m == 1 ? w_dk : w_dv)
                              : (m == 0 ? w_rq : m == 1 ? w_rk : w_rv);

        #pragma unroll
        for (int rr = 0; rr < 4; ++rr) {
            int r = rr*16 + sr;
            *(float4*)&Ws[r][sc] = *(const float4*)&W[r*64 + sc];
        }
        {
            int r = tid & 15, c0 = tid >> 4;   // 16 threads per token row
            stage_x_row(&Xs[r][0], rgb, dep, w_exp, b_exp,
                        b, tile*16 + r, strm, c0, 16);
        }
        __syncthreads();

        int ty = tid >> 4, tx = tid & 15;
        float acc[4] = {};
        #pragma unroll
        for (int k = 0; k < 64; k += 4) {
            float4 xv = *(const float4*)&Xs[ty][k];
            #pragma unroll
            for (int j = 0; j < 4; ++j) {
                float4 wv = *(const float4*)&Ws[tx + 16*j][k];
                acc[j] += xv.x*wv.x + xv.y*wv.y + xv.z*wv.z + xv.w*wv.w;
            }
        }
        float scale = (m == 0) ? (0.35355339059327373f * 1.4426950408889634f) : 1.0f;
        int n = tile*16 + ty;
        #pragma unroll
        for (int j = 0; j < 4; ++j) {
            int o = tx + 16*j;
            int h = o >> 3, d = o & 7;
            bf16_t v = f2bf(acc[j] * scale);
            if (m == 0)      Qb[(((size_t)sb*8 + h)*NTOK + n)*8 + d] = v;
            else if (m == 1) Kb[(((size_t)sb*8 + h)*NTOK + n)*8 + d] = v;
            else             VT[(((size_t)sb*8 + h)*8 + d)*NTOK + n] = v;
        }
    } else if (blockIdx.z < 2) {
        // wprep: m = blockIdx.z (0: W1=Wc[:,:64]@Wrp, 1: W2=Wc[:,64:]@Wdp),
        // bx = blockIdx.y selects the 16-row output strip.
        int m = blockIdx.z;
        int bx = blockIdx.y;
        const float* Wp = m ? w_dp : w_rp;
        float* Wo = m ? W2 : W1;
        #pragma unroll
        for (int rr = 0; rr < 4; ++rr) {
            int r = rr*16 + sr;
            *(float4*)&Ws[r][sc] = *(const float4*)&Wp[r*64 + sc];
        }
        __syncthreads();
        int r = tid >> 4;
        int o = bx*16 + r;
        int c4 = (tid & 15) * 4;
        float a0 = 0, a1 = 0, a2 = 0, a3 = 0;
        for (int j = 0; j < 64; ++j) {
            float wc = w_comp[o*128 + m*64 + j];
            float4 wp = *(const float4*)&Ws[j][c4];
            a0 += wc*wp.x; a1 += wc*wp.y; a2 += wc*wp.z; a3 += wc*wp.w;
        }
        Wo[o*64 + c4]     = a0;
        Wo[o*64 + c4 + 1] = a1;
        Wo[o*64 + c4 + 2] = a2;
        Wo[o*64 + c4 + 3] = a3;
        if (m == 0 && bx == 0 && tid < 64) {
            float s = b_comp[tid];
            for (int j = 0; j < 64; ++j)
                s += w_comp[tid*128 + j] * b_rp[j] + w_comp[tid*128 + 64 + j] * b_dp[j];
            beff[tid] = s;
        }
    } else if (blockIdx.y == 0) {
        // zero ALL 288 completion counters (strided — R26 bug fix)
        for (int i = tid; i < 288; i += 256) cnt[i] = 0;
    }
}

// MFMA flash attention (R23 proven 32-key body: swapped-operand S^T + packed
// b64 P stores) + FUSED outcomp epilogue. grid(36, 8, 4), 4 independent
// waves; wave w = qtile blockIdx.x*4+w. After the wave stores its AO slice,
// it release-fences and bumps cnt[b*144+qt]; the 16th (h,which) arrival
// acquire-fences and performs the tile's 2xK=64 GEMM + beff + GELU +
// coalesced store. No spins; value-deterministic.
__global__ __launch_bounds__(256) void attnout_kernel(
    const bf16_t* __restrict__ Qb, const bf16_t* __restrict__ Kb,
    const bf16_t* __restrict__ VT,
    float* __restrict__ AOr, float* __restrict__ AOd,
    const float* __restrict__ W1, const float* __restrict__ W2,
    const float* __restrict__ beff,
    unsigned* __restrict__ cnt,
    float* __restrict__ out)
{
    int h = blockIdx.y;
    int z = blockIdx.z;
    int b = z >> 1, which = z & 1;
    int qsb = which * 2 + b;
    int ksb = (1 - which) * 2 + b;
    const bf16_t* Q  = Qb + ((size_t)qsb * 8 + h) * NTOK * 8;
    const bf16_t* K  = Kb + ((size_t)ksb * 8 + h) * NTOK * 8;
    const bf16_t* Vt = VT + ((size_t)ksb * 8 + h) * 8 * NTOK;  // [d][key]
    float* AO = which ? AOd : AOr;

    __shared__ __align__(16) bf16_t Pls[4][16][40];  // 5 KB, rows 80 B
    __shared__ __align__(16) float  Ols[4][16][16];  // 4 KB

    int tid = threadIdx.x;
    int t = tid & 63, w = tid >> 6;
    int m16 = t & 15, quad = t >> 4;
    int qt = blockIdx.x * 4 + w;       // 0..143
    int n0 = qt * 16;

    const bf16x8 zf = {0,0,0,0,0,0,0,0};
    const bf16x8 onesf = {0x3F80,0x3F80,0x3F80,0x3F80,
                          0x3F80,0x3F80,0x3F80,0x3F80};
    const f32x4 cz = {0.f, 0.f, 0.f, 0.f};

    bf16x8 qf = (quad == 0) ? *(const bf16x8*)&Q[(size_t)(n0 + m16) * 8] : zf;

    f32x4 oacc = cz;

    #pragma unroll 1
    for (int ck = 0; ck < 72; ++ck) {
        int k0 = ck * 32;
        bf16x8 kf0 = (quad == 0) ? *(const bf16x8*)&K[(size_t)(k0 + m16) * 8]      : zf;
        bf16x8 kf1 = (quad == 0) ? *(const bf16x8*)&K[(size_t)(k0 + 16 + m16) * 8] : zf;
        bf16x8 vf = (m16 < 8) ? *(const bf16x8*)&Vt[(size_t)m16 * NTOK + k0 + quad * 8]
                  : (m16 == 8 ? onesf : zf);

        // S^T = mfma(K, Q): lane (quad,m16) holds S[key=quad*4+r][q=m16].
        f32x4 s0 = __builtin_amdgcn_mfma_f32_16x16x32_bf16(kf0, qf, cz, 0, 0, 0);
        f32x4 s1 = __builtin_amdgcn_mfma_f32_16x16x32_bf16(kf1, qf, cz, 0, 0, 0);

        bf16x4 pA, pB;
        #pragma unroll
        for (int r = 0; r < 4; ++r) {
            float p0 = __builtin_amdgcn_exp2f(s0[r]);
            float p1 = __builtin_amdgcn_exp2f(s1[r]);
            pA[r] = (short)(__float_as_uint(p0) >> 16);
            pB[r] = (short)(__float_as_uint(p1) >> 16);
        }
        *(bf16x4*)&Pls[w][m16][quad * 4]      = pA;
        *(bf16x4*)&Pls[w][m16][16 + quad * 4] = pB;

        bf16x8 pf = *(const bf16x8*)&Pls[w][m16][quad * 8];
        oacc = __builtin_amdgcn_mfma_f32_16x16x32_bf16(pf, vf, oacc, 0, 0, 0);
    }

    #pragma unroll
    for (int r = 0; r < 4; ++r)
        Ols[w][quad*4 + r][m16] = oacc[r];
    #pragma unroll
    for (int e = 0; e < 2; ++e) {
        int idx = t * 2 + e;           // 0..127 = 16 q x 8 d
        int qq = idx >> 3, d = idx & 7;
        float val = Ols[w][qq][d] / Ols[w][qq][8];
        AO[((size_t)b * NTOK + n0 + qq) * 64 + 8 * h + d] = val;
    }

    // ---- fused outcomp epilogue: last of the 16 (h,which) units closes ----
    __threadfence();
    int last = 0;
    if (t == 0) {
        unsigned old = __hip_atomic_fetch_add(&cnt[b * 144 + qt], 1u,
                           __ATOMIC_ACQ_REL, __HIP_MEMORY_SCOPE_AGENT);
        last = (old == 15u);
    }
    last = __shfl(last, 0);
    if (!last) return;
    __threadfence();

    // 16 tokens x 64 outputs. Lane (tok = t&15, kg = t>>4): partial over
    // k-chunk [16*kg, 16*kg+16); shfl_xor tree sums the 4 chunks.
    int tok = t & 15, kg = t >> 4;
    const float* ar = &AOr[((size_t)b * NTOK + n0 + tok) * 64 + kg * 16];
    const float* ad = &AOd[((size_t)b * NTOK + n0 + tok) * 64 + kg * 16];
    float xr[16], xd[16];
    #pragma unroll
    for (int i = 0; i < 16; i += 4) {
        *(float4*)&xr[i] = *(const float4*)&ar[i];
        *(float4*)&xd[i] = *(const float4*)&ad[i];
    }
    #pragma unroll 1
    for (int o = 0; o < 64; ++o) {
        const float* w1 = &W1[o * 64 + kg * 16];
        const float* w2 = &W2[o * 64 + kg * 16];
        float p = 0.f;
        #pragma unroll
        for (int i = 0; i < 16; i += 4) {
            float4 wv1 = *(const float4*)&w1[i];
            float4 wv2 = *(const float4*)&w2[i];
            p += xr[i]*wv1.x + xr[i+1]*wv1.y + xr[i+2]*wv1.z + xr[i+3]*wv1.w
               + xd[i]*wv2.x + xd[i+1]*wv2.y + xd[i+2]*wv2.z + xd[i+3]*wv2.w;
        }
        p += __shfl_xor(p, 16);
        p += __shfl_xor(p, 32);
        if (kg == (o & 3)) {
            float x = p + beff[o];
            float gl = 0.5f * x * (1.0f + erff(x * 0.70710678118654752f));
            out[((size_t)(b * C + o)) * NTOK + n0 + tok] = gl;
        }
    }
}

// ===========================================================================
// FALLBACK (R9 big path, proven): ws >= 3,538,944 B.
// ===========================================================================
__global__ __launch_bounds__(256) void kv_all_kernel(
    const float* __restrict__ rgb, const float* __restrict__ dep,
    const float* __restrict__ w_exp, const float* __restrict__ b_exp,
    const float* __restrict__ w_rk, const float* __restrict__ w_rv,
    const float* __restrict__ w_dk, const float* __restrict__ w_dv,
    bf16_t* __restrict__ Kr, bf16_t* __restrict__ Vr,
    bf16_t* __restrict__ Kd, bf16_t* __restrict__ Vd)
{
    int tile = blockIdx.x;
    int m    = blockIdx.y;
    int z    = blockIdx.z;
    int b = z >> 1, strm = z & 1;
    const float* W = strm ? (m ? w_dv : w_dk) : (m ? w_rv : w_rk);
    bf16_t* O = (strm ? (m ? Vd : Kd) : (m ? Vr : Kr))
              + ((size_t)b * NTOK + tile * 64) * 64;

    __shared__ float Xs[64][68];
    __shared__ float Ws[64][68];
    int tid = threadIdx.x;
    {
        int r = tid & 63, c0 = tid >> 6;
        stage_x_row(&Xs[r][0], rgb, dep, w_exp, b_exp, b, tile*64 + r, strm, c0, 4);
    }
    int sr = tid >> 4, sc = (tid & 15) * 4;
    #pragma unroll
    for (int rr = 0; rr < 4; ++rr) {
        int r = rr*16 + sr;
        *(float4*)&Ws[r][sc] = *(const float4*)&W[r*64 + sc];
    }
    __syncthreads();

    int ty = tid >> 4, tx = tid & 15;
    float acc[4][4] = {};
    #pragma unroll
    for (int k = 0; k < 64; k += 4) {
        float4 xv[4], wv4[4];
        #pragma unroll
        for (int i = 0; i < 4; ++i) xv[i] = *(const float4*)&Xs[4*ty + i][k];
        #pragma unroll
        for (int j = 0; j < 4; ++j) wv4[j] = *(const float4*)&Ws[tx + 16*j][k];
        #pragma unroll
        for (int i = 0; i < 4; ++i)
            #pragma unroll
            for (int j = 0; j < 4; ++j)
                acc[i][j] += xv[i].x*wv4[j].x + xv[i].y*wv4[j].y + xv[i].z*wv4[j].z + xv[i].w*wv4[j].w;
    }
    #pragma unroll
    for (int i = 0; i < 4; ++i)
        #pragma unroll
        for (int j = 0; j < 4; ++j)
            O[(4*ty + i)*64 + tx + 16*j] = f2bf(acc[i][j]);
}

__global__ __launch_bounds__(256) void attn_all_kernel(
    const float* __restrict__ rgb, const float* __restrict__ dep,
    const float* __restrict__ w_exp, const float* __restrict__ b_exp,
    const float* __restrict__ w_rq, const float* __restrict__ w_dq,
    const bf16_t* __restrict__ Kr, const bf16_t* __restrict__ Vr,
    const bf16_t* __restrict__ Kd, const bf16_t* __restrict__ Vd,
    bf16_t* __restrict__ AOr, bf16_t* __restrict__ AOd)
{
    int qt = blockIdx.x;
    int h  = blockIdx.y;
    int z  = blockIdx.z;
    int b = z >> 1, which = z & 1;
    const float* wq = which ? w_dq : w_rq;
    const bf16_t* K = which ? Kr : Kd;
    const bf16_t* V = which ? Vr : Vd;
    bf16_t* AO      = which ? AOd : AOr;

    __shared__ float Xs[64][68];
    __shared__ float Wqs[8][64];
    __shared__ __align__(16) float Ks[4][64][KVSTRIDE];
    __shared__ __align__(16) float Vs[4][64][KVSTRIDE];

    int tid = threadIdx.x;
    int t = tid & 63;
    int w = tid >> 6;
    int n = qt * 64 + t;

    stage_x_row(&Xs[t][0], rgb, dep, w_exp, b_exp, b, n, which == 0 ? 0 : 1, w, 4);
    if (w == 0) {
        #pragma unroll
        for (int d = 0; d < 8; ++d) Wqs[d][t] = wq[(8*h + d)*64 + t];
    }
    __syncthreads();

    const float sc = 0.35355339059327373f * 1.4426950408889634f;
    float q[8];
    #pragma unroll
    for (int d = 0; d < 8; ++d) {
        float s = 0.f;
        #pragma unroll 8
        for (int c = 0; c < 64; ++c) s += Xs[t][c] * Wqs[d][c];
        q[d] = s * sc;
    }

    float mrun = -INFINITY, l = 0.f;
    float acc[8] = {};

    #pragma unroll 1
    for (int st = 0; st < 9; ++st) {
        __syncthreads();
        {
            size_t g = ((size_t)b * NTOK + (w*576 + st*64 + t)) * 64 + 8 * h;
            *(float4*)&Ks[w][t][0] = ld_bf4(&K[g]);
            *(float4*)&Ks[w][t][4] = ld_bf4(&K[g + 4]);
            *(float4*)&Vs[w][t][0] = ld_bf4(&V[g]);
            *(float4*)&Vs[w][t][4] = ld_bf4(&V[g + 4]);
        }
        __syncthreads();

        for (int g8 = 0; g8 < 8; ++g8) {
            float s[8];
            #pragma unroll
            for (int u = 0; u < 8; ++u) {
                const float4 ka = *(const float4*)&Ks[w][g8*8 + u][0];
                const float4 kb = *(const float4*)&Ks[w][g8*8 + u][4];
                s[u] = q[0]*ka.x + q[1]*ka.y + q[2]*ka.z + q[3]*ka.w
                     + q[4]*kb.x + q[5]*kb.y + q[6]*kb.z + q[7]*kb.w;
            }
            float tm = fmaxf(fmaxf(fmaxf(s[0],s[1]), fmaxf(s[2],s[3])),
                             fmaxf(fmaxf(s[4],s[5]), fmaxf(s[6],s[7])));
            float mn = fmaxf(mrun, tm);
            float alpha = __builtin_amdgcn_exp2f(mrun - mn);
            float ps = 0.f;
            #pragma unroll
            for (int u = 0; u < 8; ++u) { s[u] = __builtin_amdgcn_exp2f(s[u] - mn); ps += s[u]; }
            l = l * alpha + ps;
            #pragma unroll
            for (int d = 0; d < 8; ++d) acc[d] *= alpha;
            #pragma unroll
            for (int u = 0; u < 8; ++u) {
                const float4 va = *(const float4*)&Vs[w][g8*8 + u][0];
                const float4 vb = *(const float4*)&Vs[w][g8*8 + u][4];
                acc[0] += s[u]*va.x; acc[1] += s[u]*va.y; acc[2] += s[u]*va.z; acc[3] += s[u]*va.w;
                acc[4] += s[u]*vb.x; acc[5] += s[u]*vb.y; acc[6] += s[u]*vb.z; acc[7] += s[u]*vb.w;
            }
            mrun = mn;
        }
    }

    float* part = &Xs[0][0];
    __syncthreads();
    {
        float* p = &part[(w*64 + t) * 10];
        p[0] = mrun; p[1] = l;
        #pragma unroll
        for (int d = 0; d < 8; ++d) p[2 + d] = acc[d];
    }
    __syncthreads();
    if (tid < 64) {
        float M = -INFINITY;
        #pragma unroll
        for (int v = 0; v < 4; ++v) M = fmaxf(M, part[(v*64 + t)*10]);
        float L = 0.f, o[8] = {};
        #pragma unroll
        for (int v = 0; v < 4; ++v) {
            const float* p = &part[(v*64 + t)*10];
            float al = __builtin_amdgcn_exp2f(p[0] - M);
            L += p[1] * al;
            #pragma unroll
            for (int d = 0; d < 8; ++d) o[d] += p[2 + d] * al;
        }
        float inv = 1.0f / L;
        uint4 ov;
        ov.x = pack2(o[0]*inv, o[1]*inv);
        ov.y = pack2(o[2]*inv, o[3]*inv);
        ov.z = pack2(o[4]*inv, o[5]*inv);
        ov.w = pack2(o[6]*inv, o[7]*inv);
        *(uint4*)&AO[((size_t)b * NTOK + n) * 64 + 8 * h] = ov;
    }
}

__global__ __launch_bounds__(256) void projcomp_all_kernel(
    const bf16_t* __restrict__ AOr, const bf16_t* __restrict__ AOd,
    const float* __restrict__ w_rp, const float* __restrict__ b_rp,
    const float* __restrict__ w_dp, const float* __restrict__ b_dp,
    const float* __restrict__ w_comp, const float* __restrict__ b_comp,
    float* __restrict__ out)
{
    int tile = blockIdx.x;
    int b    = blockIdx.y;
    __shared__ float A[64][68];
    __shared__ float Bf[64][68];
    __shared__ float Pf[64][68];
    int tid = threadIdx.x;
    int sr = tid >> 4, sc = (tid & 15) * 4;
    int ty = tid >> 4, tx = tid & 15;
    float G[4][4] = {};

    #pragma unroll
    for (int half = 0; half < 2; ++half) {
        const bf16_t* AOx = half ? AOd : AOr;
        const float* Wp   = half ? w_dp : w_rp;
        const float* bp   = half ? b_dp : b_rp;
        #pragma unroll
        for (int rr = 0; rr < 4; ++rr) {
            int r = rr*16 + sr;
            *(float4*)&A[r][sc]  = ld_bf4(&AOx[((size_t)b*NTOK + tile*64 + r)*64 + sc]);
            *(float4*)&Bf[r][sc] = *(const float4*)&Wp[r*64 + sc];
        }
        __syncthreads();
        float acc[4][4] = {};
        #pragma unroll
        for (int k = 0; k < 64; k += 4) {
            float4 xv[4], wv[4];
            #pragma unroll
            for (int i = 0; i < 4; ++i) xv[i] = *(const float4*)&A[4*ty + i][k];
            #pragma unroll
            for (int j = 0; j < 4; ++j) wv[j] = *(const float4*)&Bf[tx + 16*j][k];
            #pragma unroll
            for (int i = 0; i < 4; ++i)
                #pragma unroll
                for (int j = 0; j < 4; ++j)
                    acc[i][j] += xv[i].x*wv[j].x + xv[i].y*wv[j].y + xv[i].z*wv[j].z + xv[i].w*wv[j].w;
        }
        __syncthreads();
        #pragma unroll
        for (int j = 0; j < 4; ++j) {
            float bj = bp[tx + 16*j];
            #pragma unroll
            for (int i = 0; i < 4; ++i)
                Pf[4*ty + i][tx + 16*j] = acc[i][j] + bj;
        }
        #pragma unroll
        for (int rr = 0; rr < 4; ++rr) {
            int r = rr*16 + sr;
            *(float4*)&Bf[r][sc] = *(const float4*)&w_comp[r*128 + half*64 + sc];
        }
        __syncthreads();
        #pragma unroll
        for (int k = 0; k < 64; k += 4) {
            float4 xv[4], wv[4];
            #pragma unroll
            for (int i = 0; i < 4; ++i) xv[i] = *(const float4*)&Pf[4*ty + i][k];
            #pragma unroll
            for (int j = 0; j < 4; ++j) wv[j] = *(const float4*)&Bf[tx + 16*j][k];
            #pragma unroll
            for (int i = 0; i < 4; ++i)
                #pragma unroll
                for (int j = 0; j < 4; ++j)
                    G[i][j] += xv[i].x*wv[j].x + xv[i].y*wv[j].y + xv[i].z*wv[j].z + xv[i].w*wv[j].w;
        }
        __syncthreads();
    }

    #pragma unroll
    for (int j = 0; j < 4; ++j) {
        int o = tx + 16*j;
        float bj = b_comp[o];
        #pragma unroll
        for (int i = 0; i < 4; ++i) {
            int n = tile*64 + 4*ty + i;
            int wi = n / HH, hi = n % HH;
            float x = G[i][j] + bj;
            float g = 0.5f * x * (1.0f + erff(x * 0.70710678118654752f));
            out[((b*C + o)*WW + wi)*HH + hi] = g;
        }
    }
}

// ---------------------------------------------------------------------------
extern "C" void kernel_launch(void* const* d_in, const int* in_sizes, int n_in,
                              void* d_out, int out_size, void* d_ws, size_t ws_size,
                              hipStream_t stream) {
    const float* rgb_fea = (const float*)d_in[0];
    const float* depth   = (const float*)d_in[1];
    const float* w_exp   = (const float*)d_in[2];
    const float* b_exp   = (const float*)d_in[3];
    const float* w_rq    = (const float*)d_in[4];
    const float* w_rk    = (const float*)d_in[5];
    const float* w_rv    = (const float*)d_in[6];
    const float* w_dq    = (const float*)d_in[7];
    const float* w_dk    = (const float*)d_in[8];
    const float* w_dv    = (const float*)d_in[9];
    const float* w_rp    = (const float*)d_in[10];
    const float* b_rp    = (const float*)d_in[11];
    const float* w_dp    = (const float*)d_in[12];
    const float* b_dp    = (const float*)d_in[13];
    const float* w_comp  = (const float*)d_in[14];
    const float* b_comp  = (const float*)d_in[15];
    float* out = (float*)d_out;

    if (ws_size >= 5932416) {
        // Layout:
        //   0        Qb [4][8][2304][8] bf16   (1,179,648)
        //   1179648  Kb                        (1,179,648)
        //   2359296  VT [4][8][8][2304] bf16   (1,179,648)
        //   3538944  AOr+AOd [2x 2304*64] f32  (2,359,296)
        //   5898240  W1 / 5914624 W2 / 5931008 beff
        //   5931264  cnt [288] u32 (zeroed by qkvprep each replay)
        char* Wb = (char*)d_ws;
        bf16_t* Qb   = (bf16_t*)Wb;
        bf16_t* Kb   = (bf16_t*)(Wb + 1179648);
        bf16_t* VT   = (bf16_t*)(Wb + 2359296);
        float*  AOr  = (float*)(Wb + 3538944);
        float*  AOd  = AOr + 294912;
        float*  W1   = (float*)(Wb + 5898240);
        float*  W2   = (float*)(Wb + 5914624);
        float*  beff = (float*)(Wb + 5931008);
        unsigned* cnt = (unsigned*)(Wb + 5931264);

        qkvprep_kernel<<<dim3(145, 4, 3), dim3(256), 0, stream>>>(
            rgb_fea, depth, w_exp, b_exp,
            w_rq, w_rk, w_rv, w_dq, w_dk, w_dv,
            w_rp, w_dp, w_comp, b_rp, b_dp, b_comp,
            Qb, Kb, VT, W1, W2, beff, cnt);
        attnout_kernel<<<dim3(36, 8, 4), dim3(256), 0, stream>>>(
            Qb, Kb, VT, AOr, AOd, W1, W2, beff, cnt, out);
    } else {
        // R9 big path (proven)
        const size_t BUF = (size_t)BATCH * NTOK * 64;
        bf16_t* Kr  = (bf16_t*)d_ws;
        bf16_t* Vr  = Kr + BUF;
        bf16_t* Kd  = Vr + BUF;
        bf16_t* Vd  = Kd + BUF;
        bf16_t* AOr = Vd + BUF;
        bf16_t* AOd = AOr + BUF;
        kv_all_kernel<<<dim3(36, 2, 4), dim3(256), 0, stream>>>(
            rgb_fea, depth, w_exp, b_exp, w_rk, w_rv, w_dk, w_dv, Kr, Vr, Kd, Vd);
        attn_all_kernel<<<dim3(36, 8, 4), dim3(256), 0, stream>>>(
            rgb_fea, depth, w_exp, b_exp, w_rq, w_dq, Kr, Vr, Kd, Vd, AOr, AOd);
        projcomp_all_kernel<<<dim3(36, 2), dim3(256), 0, stream>>>(
            AOr, AOd, w_rp, b_rp, w_dp, b_dp, w_comp, b_comp, out);
    }
}

// Round 13
// 165.498 us; speedup vs baseline: 2.3837x; 2.3837x over previous
//
#include <hip/hip_runtime.h>
#include <math.h>

// R28: R27's fused epilogue was correct but 5.4x slower (attnout 294us,
// VALUBusy 8.8% — VALU cycles conserved): per-wave device-scope fences
// (~20K cy each, 2x4608 waves) serialized the chip. Lesson: no cross-block
// dataflow within a dispatch. Revert to proven R23 (161.5us) + the one
// untried clean lever: NO-ATOMIC K-split attn. R17's split raised occupancy
// 40->61% but was slower — confounded by atomics+memset. Here each key-half
// writes its own AO[kh] numerators + L[kh] denominators (each address
// written once; no atomics/fences/zeroing); outcomp merges
// (AO0+AO1)/(L0+L1) during staging (R17 proved the merge numerically).
// 9216 waves (36/CU vs 18). Tiered: split needs ws>=8,880,384; else exact
// R23 path; else R9. Shared templated attn body (R23 proven 32-key loop).
#define BATCH 2
#define C 64
#define HH 48
#define WW 48
#define NTOK 2304
#define HEADS 8
#define KVSTRIDE 12

typedef unsigned short bf16_t;
typedef __attribute__((ext_vector_type(8))) short bf16x8;
typedef __attribute__((ext_vector_type(4))) short bf16x4;
typedef __attribute__((ext_vector_type(4))) float f32x4;

__device__ __forceinline__ bf16_t f2bf(float f) {
    unsigned int u = __float_as_uint(f);
    u = (u + 0x7fffu + ((u >> 16) & 1u)) >> 16;   // RNE
    return (bf16_t)u;
}
__device__ __forceinline__ unsigned pack2(float a, float b) {
    return (unsigned)f2bf(a) | ((unsigned)f2bf(b) << 16);
}
__device__ __forceinline__ float4 ld_bf4(const bf16_t* p) {
    uint2 v = *(const uint2*)p;
    float4 r;
    r.x = __uint_as_float(v.x << 16); r.y = __uint_as_float(v.x & 0xffff0000u);
    r.z = __uint_as_float(v.y << 16); r.w = __uint_as_float(v.y & 0xffff0000u);
    return r;
}

// Stage one token-row of X. strm 0: rgb transpose gather. strm 1: conv1x1+
// ReLU+bilinear x2 (half-pixel; clamp == jax edge renorm for 24->48).
__device__ __forceinline__ void stage_x_row(
    float* xrow, const float* rgb, const float* dep,
    const float* w_exp, const float* b_exp,
    int b, int n, int strm, int c0, int cstep)
{
    int wi = n / HH, hi = n % HH;
    if (strm == 0) {
        const float* base = rgb + (size_t)b * C * NTOK + (size_t)hi * WW + wi;
        for (int c = c0; c < 64; c += cstep)
            xrow[c] = base[(size_t)c * NTOK];
    } else {
        float cy = 0.5f * hi - 0.25f, cx = 0.5f * wi - 0.25f;
        float fy0 = floorf(cy), fx0 = floorf(cx);
        float fy = cy - fy0, fx = cx - fx0;
        int y0 = max((int)fy0, 0), x0 = max((int)fx0, 0);
        int y1 = min((int)fy0 + 1, 23), x1 = min((int)fx0 + 1, 23);
        const float* dp = dep + b * 576;
        float d00 = dp[y0*24 + x0], d01 = dp[y0*24 + x1];
        float d10 = dp[y1*24 + x0], d11 = dp[y1*24 + x1];
        for (int c = c0; c < 64; c += cstep) {
            float w = w_exp[c], bb = b_exp[c];
            float r00 = fmaxf(w*d00 + bb, 0.f), r01 = fmaxf(w*d01 + bb, 0.f);
            float r10 = fmaxf(w*d10 + bb, 0.f), r11 = fmaxf(w*d11 + bb, 0.f);
            xrow[c] = (1.f-fy)*((1.f-fx)*r00 + fx*r01) + fy*((1.f-fx)*r10 + fx*r11);
        }
    }
}

// ===========================================================================
// MAIN PATH kernels.
// ===========================================================================

// qkvprep (R23 proven): grid(146, 4). Blocks x<144: 16-token tile x
// (b*2+strm); X gathered in-block; weights register-prefetched; 3 GEMM
// phases. Blocks 144/145: wprep task m=x-144, strip bx=blockIdx.y.
__global__ __launch_bounds__(256) void qkvprep_kernel(
    const float* __restrict__ rgb, const float* __restrict__ dep,
    const float* __restrict__ w_exp, const float* __restrict__ b_exp,
    const float* __restrict__ w_rq, const float* __restrict__ w_rk,
    const float* __restrict__ w_rv,
    const float* __restrict__ w_dq, const float* __restrict__ w_dk,
    const float* __restrict__ w_dv,
    const float* __restrict__ w_rp, const float* __restrict__ w_dp,
    const float* __restrict__ w_comp,
    const float* __restrict__ b_rp, const float* __restrict__ b_dp,
    const float* __restrict__ b_comp,
    bf16_t* __restrict__ Qb, bf16_t* __restrict__ Kb, bf16_t* __restrict__ VT,
    float* __restrict__ W1, float* __restrict__ W2, float* __restrict__ beff)
{
    __shared__ float Xs[16][68];
    __shared__ float Ws[64][68];
    int bxid = blockIdx.x;
    int tid = threadIdx.x;
    int sr = tid >> 4, sc = (tid & 15) * 4;

    if (bxid < 144) {
        int tile = bxid;
        int z = blockIdx.y;              // b*2 + strm
        int b = z >> 1, strm = z & 1;
        int sb = strm*2 + b;

        // Issue ALL weight loads first (independent of the X gather).
        float4 wreg[3][4];
        #pragma unroll
        for (int m = 0; m < 3; ++m) {
            const float* W = strm ? (m == 0 ? w_dq : m == 1 ? w_dk : w_dv)
                                  : (m == 0 ? w_rq : m == 1 ? w_rk : w_rv);
            #pragma unroll
            for (int rr = 0; rr < 4; ++rr)
                wreg[m][rr] = *(const float4*)&W[(rr*16 + sr)*64 + sc];
        }
        {
            int r = tid & 15, c0 = tid >> 4;   // 16 threads per token row
            stage_x_row(&Xs[r][0], rgb, dep, w_exp, b_exp,
                        b, tile*16 + r, strm, c0, 16);
        }

        int ty = tid >> 4, tx = tid & 15;
        #pragma unroll
        for (int m = 0; m < 3; ++m) {
            __syncthreads();   // Xs ready (m=0) / prior GEMM done reading Ws
            #pragma unroll
            for (int rr = 0; rr < 4; ++rr)
                *(float4*)&Ws[rr*16 + sr][sc] = wreg[m][rr];
            __syncthreads();

            float acc[4] = {};
            #pragma unroll
            for (int k = 0; k < 64; k += 4) {
                float4 xv = *(const float4*)&Xs[ty][k];
                #pragma unroll
                for (int j = 0; j < 4; ++j) {
                    float4 wv = *(const float4*)&Ws[tx + 16*j][k];
                    acc[j] += xv.x*wv.x + xv.y*wv.y + xv.z*wv.z + xv.w*wv.w;
                }
            }
            float scale = (m == 0) ? (0.35355339059327373f * 1.4426950408889634f) : 1.0f;
            int n = tile*16 + ty;
            #pragma unroll
            for (int j = 0; j < 4; ++j) {
                int o = tx + 16*j;
                int h = o >> 3, d = o & 7;
                bf16_t v = f2bf(acc[j] * scale);
                if (m == 0)      Qb[(((size_t)sb*8 + h)*NTOK + n)*8 + d] = v;
                else if (m == 1) Kb[(((size_t)sb*8 + h)*NTOK + n)*8 + d] = v;
                else             VT[(((size_t)sb*8 + h)*8 + d)*NTOK + n] = v;
            }
        }
    } else {
        int m = bxid - 144;
        int bx = blockIdx.y;
        const float* Wp = m ? w_dp : w_rp;
        float* Wo = m ? W2 : W1;
        #pragma unroll
        for (int rr = 0; rr < 4; ++rr) {
            int r = rr*16 + sr;
            *(float4*)&Ws[r][sc] = *(const float4*)&Wp[r*64 + sc];
        }
        __syncthreads();
        int r = tid >> 4;
        int o = bx*16 + r;
        int c4 = (tid & 15) * 4;
        float a0 = 0, a1 = 0, a2 = 0, a3 = 0;
        for (int j = 0; j < 64; ++j) {
            float wc = w_comp[o*128 + m*64 + j];
            float4 wp = *(const float4*)&Ws[j][c4];
            a0 += wc*wp.x; a1 += wc*wp.y; a2 += wc*wp.z; a3 += wc*wp.w;
        }
        Wo[o*64 + c4]     = a0;
        Wo[o*64 + c4 + 1] = a1;
        Wo[o*64 + c4 + 2] = a2;
        Wo[o*64 + c4 + 3] = a3;
        if (m == 0 && bx == 0 && tid < 64) {
            float s = b_comp[tid];
            for (int j = 0; j < 64; ++j)
                s += w_comp[tid*128 + j] * b_rp[j] + w_comp[tid*128 + 64 + j] * b_dp[j];
            beff[tid] = s;
        }
    }
}

// MFMA flash attention, templated on K-split. Body = R23 proven 32-key
// loop (swapped-operand S^T + packed b64 P stores). 4 independent waves.
// SPLIT=false: grid(36,8,4); full 72 chunks; normalize and write AO.
// SPLIT=true:  grid(72,8,4); kh=bx&1 picks 36 chunks; write raw numerators
//              to AOall[kh*2+which] and denominators to Lall[kh*2+which].
//              Every address written exactly once -> no atomics/fences.
template<bool SPLIT>
__global__ __launch_bounds__(256) void attn_kernel_t(
    const bf16_t* __restrict__ Qb, const bf16_t* __restrict__ Kb,
    const bf16_t* __restrict__ VT,
    float* __restrict__ AOall, float* __restrict__ Lall)
{
    int h = blockIdx.y;
    int z = blockIdx.z;
    int b = z >> 1, which = z & 1;
    int qsb = which * 2 + b;
    int ksb = (1 - which) * 2 + b;
    const bf16_t* Q  = Qb + ((size_t)qsb * 8 + h) * NTOK * 8;
    const bf16_t* K  = Kb + ((size_t)ksb * 8 + h) * NTOK * 8;
    const bf16_t* Vt = VT + ((size_t)ksb * 8 + h) * 8 * NTOK;  // [d][key]

    __shared__ __align__(16) bf16_t Pls[4][16][40];  // 5 KB, rows 80 B
    __shared__ __align__(16) float  Ols[4][16][16];  // 4 KB

    int tid = threadIdx.x;
    int t = tid & 63, w = tid >> 6;
    int m16 = t & 15, quad = t >> 4;

    int qt, kh, ck0;
    if (SPLIT) { qt = (blockIdx.x >> 1) * 4 + w; kh = blockIdx.x & 1; ck0 = kh * 36; }
    else       { qt = blockIdx.x * 4 + w;        kh = 0;              ck0 = 0; }
    int nck = SPLIT ? 36 : 72;
    int n0 = qt * 16;

    const bf16x8 zf = {0,0,0,0,0,0,0,0};
    const bf16x8 onesf = {0x3F80,0x3F80,0x3F80,0x3F80,
                          0x3F80,0x3F80,0x3F80,0x3F80};
    const f32x4 cz = {0.f, 0.f, 0.f, 0.f};

    bf16x8 qf = (quad == 0) ? *(const bf16x8*)&Q[(size_t)(n0 + m16) * 8] : zf;

    f32x4 oacc = cz;

    #pragma unroll 1
    for (int ci = 0; ci < nck; ++ci) {
        int k0 = (ck0 + ci) * 32;
        bf16x8 kf0 = (quad == 0) ? *(const bf16x8*)&K[(size_t)(k0 + m16) * 8]      : zf;
        bf16x8 kf1 = (quad == 0) ? *(const bf16x8*)&K[(size_t)(k0 + 16 + m16) * 8] : zf;
        bf16x8 vf = (m16 < 8) ? *(const bf16x8*)&Vt[(size_t)m16 * NTOK + k0 + quad * 8]
                  : (m16 == 8 ? onesf : zf);

        // S^T = mfma(K, Q): lane (quad,m16) holds S[key=quad*4+r][q=m16].
        f32x4 s0 = __builtin_amdgcn_mfma_f32_16x16x32_bf16(kf0, qf, cz, 0, 0, 0);
        f32x4 s1 = __builtin_amdgcn_mfma_f32_16x16x32_bf16(kf1, qf, cz, 0, 0, 0);

        bf16x4 pA, pB;
        #pragma unroll
        for (int r = 0; r < 4; ++r) {
            float p0 = __builtin_amdgcn_exp2f(s0[r]);
            float p1 = __builtin_amdgcn_exp2f(s1[r]);
            pA[r] = (short)(__float_as_uint(p0) >> 16);
            pB[r] = (short)(__float_as_uint(p1) >> 16);
        }
        *(bf16x4*)&Pls[w][m16][quad * 4]      = pA;
        *(bf16x4*)&Pls[w][m16][16 + quad * 4] = pB;

        bf16x8 pf = *(const bf16x8*)&Pls[w][m16][quad * 8];
        oacc = __builtin_amdgcn_mfma_f32_16x16x32_bf16(pf, vf, oacc, 0, 0, 0);
    }

    #pragma unroll
    for (int r = 0; r < 4; ++r)
        Ols[w][quad*4 + r][m16] = oacc[r];

    if (SPLIT) {
        float* AO = AOall + (size_t)(kh*2 + which) * BATCH * NTOK * 64;
        float* Lx = Lall  + (size_t)(kh*2 + which) * BATCH * NTOK * 8;
        #pragma unroll
        for (int e = 0; e < 2; ++e) {
            int idx = t * 2 + e;           // 16 q x 8 d
            int qq = idx >> 3, d = idx & 7;
            AO[((size_t)b * NTOK + n0 + qq) * 64 + 8 * h + d] = Ols[w][qq][d];
        }
        if (t < 16)
            Lx[((size_t)b * NTOK + n0 + t) * 8 + h] = Ols[w][t][8];
    } else {
        float* AO = AOall + (size_t)which * BATCH * NTOK * 64;
        #pragma unroll
        for (int e = 0; e < 2; ++e) {
            int idx = t * 2 + e;
            int qq = idx >> 3, d = idx & 7;
            float val = Ols[w][qq][d] / Ols[w][qq][8];
            AO[((size_t)b * NTOK + n0 + qq) * 64 + 8 * h + d] = val;
        }
    }
}

// outcomp (R23 proven): grid(144,2), 16-token tiles; AO normalized fp32.
__global__ __launch_bounds__(256) void outcomp_kernel(
    const float* __restrict__ AOr, const float* __restrict__ AOd,
    const float* __restrict__ W1, const float* __restrict__ W2,
    const float* __restrict__ beff, float* __restrict__ out)
{
    int tile = blockIdx.x;       // 0..143
    int b    = blockIdx.y;
    int n0 = tile * 16;
    __shared__ float Ar[16][68];
    __shared__ float Ad[16][68];
    __shared__ float W1s[64][68];
    __shared__ float W2s[64][68];
    int tid = threadIdx.x;
    {
        int row = tid >> 4, c4 = (tid & 15) * 4;
        size_t base = (size_t)b*NTOK + n0 + row;
        *(float4*)&Ar[row][c4] = *(const float4*)&AOr[base*64 + c4];
        *(float4*)&Ad[row][c4] = *(const float4*)&AOd[base*64 + c4];
    }
    {
        int sr = tid >> 4, sc4 = (tid & 15) * 4;
        #pragma unroll
        for (int rr = 0; rr < 4; ++rr) {
            int r = rr*16 + sr;
            *(float4*)&W1s[r][sc4] = *(const float4*)&W1[r*64 + sc4];
            *(float4*)&W2s[r][sc4] = *(const float4*)&W2[r*64 + sc4];
        }
    }
    __syncthreads();

    int tx = tid & 15, ty = tid >> 4;
    float g[4] = {};
    #pragma unroll
    for (int k = 0; k < 64; k += 4) {
        float4 xr = *(const float4*)&Ar[ty][k];
        float4 xd = *(const float4*)&Ad[ty][k];
        #pragma unroll
        for (int jj = 0; jj < 4; ++jj) {
            float4 w1 = *(const float4*)&W1s[tx + 16*jj][k];
            float4 w2 = *(const float4*)&W2s[tx + 16*jj][k];
            g[jj] += xr.x*w1.x + xr.y*w1.y + xr.z*w1.z + xr.w*w1.w
                   + xd.x*w2.x + xd.y*w2.y + xd.z*w2.z + xd.w*w2.w;
        }
    }

    __syncthreads();                   // done reading W1s/W2s
    float* Gs = &W1s[0][0];            // viewed as [64 o][stride 20]
    #pragma unroll
    for (int jj = 0; jj < 4; ++jj) {
        int o = tx + 16*jj;
        float x = g[jj] + beff[o];
        float gl = 0.5f * x * (1.0f + erff(x * 0.70710678118654752f));
        Gs[o*20 + ty] = gl;
    }
    __syncthreads();
    {
        int o = tid >> 2, s = tid & 3;  // 64 o x 4 float4-segments
        float4 v = *(const float4*)&Gs[o*20 + 4*s];
        *(float4*)&out[((size_t)(b*C + o))*NTOK + n0 + 4*s] = v;
    }
}

// outcomp for the K-split path: merge (AO0+AO1)/(L0+L1) during staging
// (merge structure proven in R17). grid(144,2).
__global__ __launch_bounds__(256) void outcomp2_kernel(
    const float* __restrict__ AOall, const float* __restrict__ Lall,
    const float* __restrict__ W1, const float* __restrict__ W2,
    const float* __restrict__ beff, float* __restrict__ out)
{
    int tile = blockIdx.x;       // 0..143
    int b    = blockIdx.y;
    int n0 = tile * 16;
    __shared__ float Ar[16][68];
    __shared__ float Ad[16][68];
    __shared__ float W1s[64][68];
    __shared__ float W2s[64][68];
    int tid = threadIdx.x;
    {
        const size_t S  = (size_t)BATCH * NTOK * 64;
        const size_t SL = (size_t)BATCH * NTOK * 8;
        int row = tid >> 4, c4 = (tid & 15) * 4;
        size_t base = (size_t)b*NTOK + n0 + row;
        int hh = c4 >> 3;
        // kh*2+which indices: (0,r)=0 (0,d)=1 (1,r)=2 (1,d)=3
        float4 r0 = *(const float4*)&AOall[0*S + base*64 + c4];
        float4 r1 = *(const float4*)&AOall[2*S + base*64 + c4];
        float4 d0 = *(const float4*)&AOall[1*S + base*64 + c4];
        float4 d1 = *(const float4*)&AOall[3*S + base*64 + c4];
        float lr = Lall[0*SL + base*8 + hh] + Lall[2*SL + base*8 + hh];
        float ld = Lall[1*SL + base*8 + hh] + Lall[3*SL + base*8 + hh];
        float ir = 1.0f / lr, id = 1.0f / ld;
        float4 vr, vd;
        vr.x = (r0.x + r1.x) * ir; vr.y = (r0.y + r1.y) * ir;
        vr.z = (r0.z + r1.z) * ir; vr.w = (r0.w + r1.w) * ir;
        vd.x = (d0.x + d1.x) * id; vd.y = (d0.y + d1.y) * id;
        vd.z = (d0.z + d1.z) * id; vd.w = (d0.w + d1.w) * id;
        *(float4*)&Ar[row][c4] = vr;
        *(float4*)&Ad[row][c4] = vd;
    }
    {
        int sr = tid >> 4, sc4 = (tid & 15) * 4;
        #pragma unroll
        for (int rr = 0; rr < 4; ++rr) {
            int r = rr*16 + sr;
            *(float4*)&W1s[r][sc4] = *(const float4*)&W1[r*64 + sc4];
            *(float4*)&W2s[r][sc4] = *(const float4*)&W2[r*64 + sc4];
        }
    }
    __syncthreads();

    int tx = tid & 15, ty = tid >> 4;
    float g[4] = {};
    #pragma unroll
    for (int k = 0; k < 64; k += 4) {
        float4 xr = *(const float4*)&Ar[ty][k];
        float4 xd = *(const float4*)&Ad[ty][k];
        #pragma unroll
        for (int jj = 0; jj < 4; ++jj) {
            float4 w1 = *(const float4*)&W1s[tx + 16*jj][k];
            float4 w2 = *(const float4*)&W2s[tx + 16*jj][k];
            g[jj] += xr.x*w1.x + xr.y*w1.y + xr.z*w1.z + xr.w*w1.w
                   + xd.x*w2.x + xd.y*w2.y + xd.z*w2.z + xd.w*w2.w;
        }
    }

    __syncthreads();
    float* Gs = &W1s[0][0];            // [64 o][stride 20]
    #pragma unroll
    for (int jj = 0; jj < 4; ++jj) {
        int o = tx + 16*jj;
        float x = g[jj] + beff[o];
        float gl = 0.5f * x * (1.0f + erff(x * 0.70710678118654752f));
        Gs[o*20 + ty] = gl;
    }
    __syncthreads();
    {
        int o = tid >> 2, s = tid & 3;
        float4 v = *(const float4*)&Gs[o*20 + 4*s];
        *(float4*)&out[((size_t)(b*C + o))*NTOK + n0 + 4*s] = v;
    }
}

// ===========================================================================
// FALLBACK (R9 big path, proven): ws >= 3,538,944 B.
// ===========================================================================
__global__ __launch_bounds__(256) void kv_all_kernel(
    const float* __restrict__ rgb, const float* __restrict__ dep,
    const float* __restrict__ w_exp, const float* __restrict__ b_exp,
    const float* __restrict__ w_rk, const float* __restrict__ w_rv,
    const float* __restrict__ w_dk, const float* __restrict__ w_dv,
    bf16_t* __restrict__ Kr, bf16_t* __restrict__ Vr,
    bf16_t* __restrict__ Kd, bf16_t* __restrict__ Vd)
{
    int tile = blockIdx.x;
    int m    = blockIdx.y;
    int z    = blockIdx.z;
    int b = z >> 1, strm = z & 1;
    const float* W = strm ? (m ? w_dv : w_dk) : (m ? w_rv : w_rk);
    bf16_t* O = (strm ? (m ? Vd : Kd) : (m ? Vr : Kr))
              + ((size_t)b * NTOK + tile * 64) * 64;

    __shared__ float Xs[64][68];
    __shared__ float Ws[64][68];
    int tid = threadIdx.x;
    {
        int r = tid & 63, c0 = tid >> 6;
        stage_x_row(&Xs[r][0], rgb, dep, w_exp, b_exp, b, tile*64 + r, strm, c0, 4);
    }
    int sr = tid >> 4, sc = (tid & 15) * 4;
    #pragma unroll
    for (int rr = 0; rr < 4; ++rr) {
        int r = rr*16 + sr;
        *(float4*)&Ws[r][sc] = *(const float4*)&W[r*64 + sc];
    }
    __syncthreads();

    int ty = tid >> 4, tx = tid & 15;
    float acc[4][4] = {};
    #pragma unroll
    for (int k = 0; k < 64; k += 4) {
        float4 xv[4], wv4[4];
        #pragma unroll
        for (int i = 0; i < 4; ++i) xv[i] = *(const float4*)&Xs[4*ty + i][k];
        #pragma unroll
        for (int j = 0; j < 4; ++j) wv4[j] = *(const float4*)&Ws[tx + 16*j][k];
        #pragma unroll
        for (int i = 0; i < 4; ++i)
            #pragma unroll
            for (int j = 0; j < 4; ++j)
                acc[i][j] += xv[i].x*wv4[j].x + xv[i].y*wv4[j].y + xv[i].z*wv4[j].z + xv[i].w*wv4[j].w;
    }
    #pragma unroll
    for (int i = 0; i < 4; ++i)
        #pragma unroll
        for (int j = 0; j < 4; ++j)
            O[(4*ty + i)*64 + tx + 16*j] = f2bf(acc[i][j]);
}

__global__ __launch_bounds__(256) void attn_all_kernel(
    const float* __restrict__ rgb, const float* __restrict__ dep,
    const float* __restrict__ w_exp, const float* __restrict__ b_exp,
    const float* __restrict__ w_rq, const float* __restrict__ w_dq,
    const bf16_t* __restrict__ Kr, const bf16_t* __restrict__ Vr,
    const bf16_t* __restrict__ Kd, const bf16_t* __restrict__ Vd,
    bf16_t* __restrict__ AOr, bf16_t* __restrict__ AOd)
{
    int qt = blockIdx.x;
    int h  = blockIdx.y;
    int z  = blockIdx.z;
    int b = z >> 1, which = z & 1;
    const float* wq = which ? w_dq : w_rq;
    const bf16_t* K = which ? Kr : Kd;
    const bf16_t* V = which ? Vr : Vd;
    bf16_t* AO      = which ? AOd : AOr;

    __shared__ float Xs[64][68];
    __shared__ float Wqs[8][64];
    __shared__ __align__(16) float Ks[4][64][KVSTRIDE];
    __shared__ __align__(16) float Vs[4][64][KVSTRIDE];

    int tid = threadIdx.x;
    int t = tid & 63;
    int w = tid >> 6;
    int n = qt * 64 + t;

    stage_x_row(&Xs[t][0], rgb, dep, w_exp, b_exp, b, n, which == 0 ? 0 : 1, w, 4);
    if (w == 0) {
        #pragma unroll
        for (int d = 0; d < 8; ++d) Wqs[d][t] = wq[(8*h + d)*64 + t];
    }
    __syncthreads();

    const float sc = 0.35355339059327373f * 1.4426950408889634f;
    float q[8];
    #pragma unroll
    for (int d = 0; d < 8; ++d) {
        float s = 0.f;
        #pragma unroll 8
        for (int c = 0; c < 64; ++c) s += Xs[t][c] * Wqs[d][c];
        q[d] = s * sc;
    }

    float mrun = -INFINITY, l = 0.f;
    float acc[8] = {};

    #pragma unroll 1
    for (int st = 0; st < 9; ++st) {
        __syncthreads();
        {
            size_t g = ((size_t)b * NTOK + (w*576 + st*64 + t)) * 64 + 8 * h;
            *(float4*)&Ks[w][t][0] = ld_bf4(&K[g]);
            *(float4*)&Ks[w][t][4] = ld_bf4(&K[g + 4]);
            *(float4*)&Vs[w][t][0] = ld_bf4(&V[g]);
            *(float4*)&Vs[w][t][4] = ld_bf4(&V[g + 4]);
        }
        __syncthreads();

        for (int g8 = 0; g8 < 8; ++g8) {
            float s[8];
            #pragma unroll
            for (int u = 0; u < 8; ++u) {
                const float4 ka = *(const float4*)&Ks[w][g8*8 + u][0];
                const float4 kb = *(const float4*)&Ks[w][g8*8 + u][4];
                s[u] = q[0]*ka.x + q[1]*ka.y + q[2]*ka.z + q[3]*ka.w
                     + q[4]*kb.x + q[5]*kb.y + q[6]*kb.z + q[7]*kb.w;
            }
            float tm = fmaxf(fmaxf(fmaxf(s[0],s[1]), fmaxf(s[2],s[3])),
                             fmaxf(fmaxf(s[4],s[5]), fmaxf(s[6],s[7])));
            float mn = fmaxf(mrun, tm);
            float alpha = __builtin_amdgcn_exp2f(mrun - mn);
            float ps = 0.f;
            #pragma unroll
            for (int u = 0; u < 8; ++u) { s[u] = __builtin_amdgcn_exp2f(s[u] - mn); ps += s[u]; }
            l = l * alpha + ps;
            #pragma unroll
            for (int d = 0; d < 8; ++d) acc[d] *= alpha;
            #pragma unroll
            for (int u = 0; u < 8; ++u) {
                const float4 va = *(const float4*)&Vs[w][g8*8 + u][0];
                const float4 vb = *(const float4*)&Vs[w][g8*8 + u][4];
                acc[0] += s[u]*va.x; acc[1] += s[u]*va.y; acc[2] += s[u]*va.z; acc[3] += s[u]*va.w;
                acc[4] += s[u]*vb.x; acc[5] += s[u]*vb.y; acc[6] += s[u]*vb.z; acc[7] += s[u]*vb.w;
            }
            mrun = mn;
        }
    }

    float* part = &Xs[0][0];
    __syncthreads();
    {
        float* p = &part[(w*64 + t) * 10];
        p[0] = mrun; p[1] = l;
        #pragma unroll
        for (int d = 0; d < 8; ++d) p[2 + d] = acc[d];
    }
    __syncthreads();
    if (tid < 64) {
        float M = -INFINITY;
        #pragma unroll
        for (int v = 0; v < 4; ++v) M = fmaxf(M, part[(v*64 + t)*10]);
        float L = 0.f, o[8] = {};
        #pragma unroll
        for (int v = 0; v < 4; ++v) {
            const float* p = &part[(v*64 + t)*10];
            float al = __builtin_amdgcn_exp2f(p[0] - M);
            L += p[1] * al;
            #pragma unroll
            for (int d = 0; d < 8; ++d) o[d] += p[2 + d] * al;
        }
        float inv = 1.0f / L;
        uint4 ov;
        ov.x = pack2(o[0]*inv, o[1]*inv);
        ov.y = pack2(o[2]*inv, o[3]*inv);
        ov.z = pack2(o[4]*inv, o[5]*inv);
        ov.w = pack2(o[6]*inv, o[7]*inv);
        *(uint4*)&AO[((size_t)b * NTOK + n) * 64 + 8 * h] = ov;
    }
}

__global__ __launch_bounds__(256) void projcomp_all_kernel(
    const bf16_t* __restrict__ AOr, const bf16_t* __restrict__ AOd,
    const float* __restrict__ w_rp, const float* __restrict__ b_rp,
    const float* __restrict__ w_dp, const float* __restrict__ b_dp,
    const float* __restrict__ w_comp, const float* __restrict__ b_comp,
    float* __restrict__ out)
{
    int tile = blockIdx.x;
    int b    = blockIdx.y;
    __shared__ float A[64][68];
    __shared__ float Bf[64][68];
    __shared__ float Pf[64][68];
    int tid = threadIdx.x;
    int sr = tid >> 4, sc = (tid & 15) * 4;
    int ty = tid >> 4, tx = tid & 15;
    float G[4][4] = {};

    #pragma unroll
    for (int half = 0; half < 2; ++half) {
        const bf16_t* AOx = half ? AOd : AOr;
        const float* Wp   = half ? w_dp : w_rp;
        const float* bp   = half ? b_dp : b_rp;
        #pragma unroll
        for (int rr = 0; rr < 4; ++rr) {
            int r = rr*16 + sr;
            *(float4*)&A[r][sc]  = ld_bf4(&AOx[((size_t)b*NTOK + tile*64 + r)*64 + sc]);
            *(float4*)&Bf[r][sc] = *(const float4*)&Wp[r*64 + sc];
        }
        __syncthreads();
        float acc[4][4] = {};
        #pragma unroll
        for (int k = 0; k < 64; k += 4) {
            float4 xv[4], wv[4];
            #pragma unroll
            for (int i = 0; i < 4; ++i) xv[i] = *(const float4*)&A[4*ty + i][k];
            #pragma unroll
            for (int j = 0; j < 4; ++j) wv[j] = *(const float4*)&Bf[tx + 16*j][k];
            #pragma unroll
            for (int i = 0; i < 4; ++i)
                #pragma unroll
                for (int j = 0; j < 4; ++j)
                    acc[i][j] += xv[i].x*wv[j].x + xv[i].y*wv[j].y + xv[i].z*wv[j].z + xv[i].w*wv[j].w;
        }
        __syncthreads();
        #pragma unroll
        for (int j = 0; j < 4; ++j) {
            float bj = bp[tx + 16*j];
            #pragma unroll
            for (int i = 0; i < 4; ++i)
                Pf[4*ty + i][tx + 16*j] = acc[i][j] + bj;
        }
        #pragma unroll
        for (int rr = 0; rr < 4; ++rr) {
            int r = rr*16 + sr;
            *(float4*)&Bf[r][sc] = *(const float4*)&w_comp[r*128 + half*64 + sc];
        }
        __syncthreads();
        #pragma unroll
        for (int k = 0; k < 64; k += 4) {
            float4 xv[4], wv[4];
            #pragma unroll
            for (int i = 0; i < 4; ++i) xv[i] = *(const float4*)&Pf[4*ty + i][k];
            #pragma unroll
            for (int j = 0; j < 4; ++j) wv[j] = *(const float4*)&Bf[tx + 16*j][k];
            #pragma unroll
            for (int i = 0; i < 4; ++i)
                #pragma unroll
                for (int j = 0; j < 4; ++j)
                    G[i][j] += xv[i].x*wv[j].x + xv[i].y*wv[j].y + xv[i].z*wv[j].z + xv[i].w*wv[j].w;
        }
        __syncthreads();
    }

    #pragma unroll
    for (int j = 0; j < 4; ++j) {
        int o = tx + 16*j;
        float bj = b_comp[o];
        #pragma unroll
        for (int i = 0; i < 4; ++i) {
            int n = tile*64 + 4*ty + i;
            int wi = n / HH, hi = n % HH;
            float x = G[i][j] + bj;
            float g = 0.5f * x * (1.0f + erff(x * 0.70710678118654752f));
            out[((b*C + o)*WW + wi)*HH + hi] = g;
        }
    }
}

// ---------------------------------------------------------------------------
extern "C" void kernel_launch(void* const* d_in, const int* in_sizes, int n_in,
                              void* d_out, int out_size, void* d_ws, size_t ws_size,
                              hipStream_t stream) {
    const float* rgb_fea = (const float*)d_in[0];
    const float* depth   = (const float*)d_in[1];
    const float* w_exp   = (const float*)d_in[2];
    const float* b_exp   = (const float*)d_in[3];
    const float* w_rq    = (const float*)d_in[4];
    const float* w_rk    = (const float*)d_in[5];
    const float* w_rv    = (const float*)d_in[6];
    const float* w_dq    = (const float*)d_in[7];
    const float* w_dk    = (const float*)d_in[8];
    const float* w_dv    = (const float*)d_in[9];
    const float* w_rp    = (const float*)d_in[10];
    const float* b_rp    = (const float*)d_in[11];
    const float* w_dp    = (const float*)d_in[12];
    const float* b_dp    = (const float*)d_in[13];
    const float* w_comp  = (const float*)d_in[14];
    const float* b_comp  = (const float*)d_in[15];
    float* out = (float*)d_out;

    if (ws_size >= 8880384) {
        // K-split tier:
        //   0         Qb/Kb/VT bf16 (3,538,944)
        //   3,538,944 AOall [4][2][2304][64] f32 (4,718,592)  idx kh*2+which
        //   8,257,536 Lall  [4][2][2304][8]  f32 (589,824)
        //   8,847,360 W1 / 8,863,744 W2 / 8,880,128 beff
        char* Wb = (char*)d_ws;
        bf16_t* Qb    = (bf16_t*)Wb;
        bf16_t* Kb    = (bf16_t*)(Wb + 1179648);
        bf16_t* VT    = (bf16_t*)(Wb + 2359296);
        float*  AOall = (float*)(Wb + 3538944);
        float*  Lall  = (float*)(Wb + 8257536);
        float*  W1    = (float*)(Wb + 8847360);
        float*  W2    = (float*)(Wb + 8863744);
        float*  beff  = (float*)(Wb + 8880128);

        qkvprep_kernel<<<dim3(146, 4), dim3(256), 0, stream>>>(
            rgb_fea, depth, w_exp, b_exp,
            w_rq, w_rk, w_rv, w_dq, w_dk, w_dv,
            w_rp, w_dp, w_comp, b_rp, b_dp, b_comp,
            Qb, Kb, VT, W1, W2, beff);
        attn_kernel_t<true><<<dim3(72, 8, 4), dim3(256), 0, stream>>>(
            Qb, Kb, VT, AOall, Lall);
        outcomp2_kernel<<<dim3(144, 2), dim3(256), 0, stream>>>(
            AOall, Lall, W1, W2, beff, out);
    } else if (ws_size >= 5931264) {
        // R23 proven tier (161.5us):
        char* Wb = (char*)d_ws;
        bf16_t* Qb   = (bf16_t*)Wb;
        bf16_t* Kb   = (bf16_t*)(Wb + 1179648);
        bf16_t* VT   = (bf16_t*)(Wb + 2359296);
        float*  AOr  = (float*)(Wb + 3538944);
        float*  AOd  = AOr + 294912;
        float*  W1   = (float*)(Wb + 5898240);
        float*  W2   = (float*)(Wb + 5914624);
        float*  beff = (float*)(Wb + 5931008);

        qkvprep_kernel<<<dim3(146, 4), dim3(256), 0, stream>>>(
            rgb_fea, depth, w_exp, b_exp,
            w_rq, w_rk, w_rv, w_dq, w_dk, w_dv,
            w_rp, w_dp, w_comp, b_rp, b_dp, b_comp,
            Qb, Kb, VT, W1, W2, beff);
        attn_kernel_t<false><<<dim3(36, 8, 4), dim3(256), 0, stream>>>(
            Qb, Kb, VT, AOr, (float*)nullptr);
        outcomp_kernel<<<dim3(144, 2), dim3(256), 0, stream>>>(
            AOr, AOd, W1, W2, beff, out);
    } else {
        // R9 big path (proven)
        const size_t BUF = (size_t)BATCH * NTOK * 64;
        bf16_t* Kr  = (bf16_t*)d_ws;
        bf16_t* Vr  = Kr + BUF;
        bf16_t* Kd  = Vr + BUF;
        bf16_t* Vd  = Kd + BUF;
        bf16_t* AOr = Vd + BUF;
        bf16_t* AOd = AOr + BUF;
        kv_all_kernel<<<dim3(36, 2, 4), dim3(256), 0, stream>>>(
            rgb_fea, depth, w_exp, b_exp, w_rk, w_rv, w_dk, w_dv, Kr, Vr, Kd, Vd);
        attn_all_kernel<<<dim3(36, 8, 4), dim3(256), 0, stream>>>(
            rgb_fea, depth, w_exp, b_exp, w_rq, w_dq, Kr, Vr, Kd, Vd, AOr, AOd);
        projcomp_all_kernel<<<dim3(36, 2), dim3(256), 0, stream>>>(
            AOr, AOd, w_rp, b_rp, w_dp, b_dp, w_comp, b_comp, out);
    }
}

// Round 14
// 161.215 us; speedup vs baseline: 2.4471x; 1.0266x over previous
//
#include <hip/hip_runtime.h>
#include <math.h>

// R29 (FINAL PIN): R28's no-atomic K-split was the last untested lever —
// occupancy 40->60%, waves x2, work/wave /2 -> duration IDENTICAL (56.5 vs
// 54.4us). Every attn lever now falsified by measurement: occupancy (R17,
// R28), prefetch (R21), LDS ops /3 (R22), ILP x2 (R25), fence-fusion (R27,
// 5.4x worse). Conserved: dur x VALUBusy ~= 21us VALU-busy = full exp2+pack
// op count at ~1.2-1.3GHz effective clock. Every dispatch ~45-55us quasi-
// fixed regardless of content; 3 dispatches = structural minimum without
// cross-block sync. 3 x ~53us ~= 161us = measured floor (last 5 rounds all
// within +-2%). This round pins the BEST measured configuration (R23 tier,
// 161.5us): non-split attn + R23 qkvprep/outcomp; split tier removed.
#define BATCH 2
#define C 64
#define HH 48
#define WW 48
#define NTOK 2304
#define HEADS 8
#define KVSTRIDE 12

typedef unsigned short bf16_t;
typedef __attribute__((ext_vector_type(8))) short bf16x8;
typedef __attribute__((ext_vector_type(4))) short bf16x4;
typedef __attribute__((ext_vector_type(4))) float f32x4;

__device__ __forceinline__ bf16_t f2bf(float f) {
    unsigned int u = __float_as_uint(f);
    u = (u + 0x7fffu + ((u >> 16) & 1u)) >> 16;   // RNE
    return (bf16_t)u;
}
__device__ __forceinline__ unsigned pack2(float a, float b) {
    return (unsigned)f2bf(a) | ((unsigned)f2bf(b) << 16);
}
__device__ __forceinline__ float4 ld_bf4(const bf16_t* p) {
    uint2 v = *(const uint2*)p;
    float4 r;
    r.x = __uint_as_float(v.x << 16); r.y = __uint_as_float(v.x & 0xffff0000u);
    r.z = __uint_as_float(v.y << 16); r.w = __uint_as_float(v.y & 0xffff0000u);
    return r;
}

// Stage one token-row of X. strm 0: rgb transpose gather. strm 1: conv1x1+
// ReLU+bilinear x2 (half-pixel; clamp == jax edge renorm for 24->48).
__device__ __forceinline__ void stage_x_row(
    float* xrow, const float* rgb, const float* dep,
    const float* w_exp, const float* b_exp,
    int b, int n, int strm, int c0, int cstep)
{
    int wi = n / HH, hi = n % HH;
    if (strm == 0) {
        const float* base = rgb + (size_t)b * C * NTOK + (size_t)hi * WW + wi;
        for (int c = c0; c < 64; c += cstep)
            xrow[c] = base[(size_t)c * NTOK];
    } else {
        float cy = 0.5f * hi - 0.25f, cx = 0.5f * wi - 0.25f;
        float fy0 = floorf(cy), fx0 = floorf(cx);
        float fy = cy - fy0, fx = cx - fx0;
        int y0 = max((int)fy0, 0), x0 = max((int)fx0, 0);
        int y1 = min((int)fy0 + 1, 23), x1 = min((int)fx0 + 1, 23);
        const float* dp = dep + b * 576;
        float d00 = dp[y0*24 + x0], d01 = dp[y0*24 + x1];
        float d10 = dp[y1*24 + x0], d11 = dp[y1*24 + x1];
        for (int c = c0; c < 64; c += cstep) {
            float w = w_exp[c], bb = b_exp[c];
            float r00 = fmaxf(w*d00 + bb, 0.f), r01 = fmaxf(w*d01 + bb, 0.f);
            float r10 = fmaxf(w*d10 + bb, 0.f), r11 = fmaxf(w*d11 + bb, 0.f);
            xrow[c] = (1.f-fy)*((1.f-fx)*r00 + fx*r01) + fy*((1.f-fx)*r10 + fx*r11);
        }
    }
}

// ===========================================================================
// MAIN PATH: 3 dispatches (qkvprep, attn, outcomp). R23-proven (161.5us).
// ===========================================================================

// qkvprep: grid(146, 4). Blocks x<144: 16-token tile x (b*2+strm); X
// gathered in-block; weights register-prefetched upfront; 3 GEMM phases.
// Blocks 144/145: wprep task m=x-144, strip bx=blockIdx.y.
__global__ __launch_bounds__(256) void qkvprep_kernel(
    const float* __restrict__ rgb, const float* __restrict__ dep,
    const float* __restrict__ w_exp, const float* __restrict__ b_exp,
    const float* __restrict__ w_rq, const float* __restrict__ w_rk,
    const float* __restrict__ w_rv,
    const float* __restrict__ w_dq, const float* __restrict__ w_dk,
    const float* __restrict__ w_dv,
    const float* __restrict__ w_rp, const float* __restrict__ w_dp,
    const float* __restrict__ w_comp,
    const float* __restrict__ b_rp, const float* __restrict__ b_dp,
    const float* __restrict__ b_comp,
    bf16_t* __restrict__ Qb, bf16_t* __restrict__ Kb, bf16_t* __restrict__ VT,
    float* __restrict__ W1, float* __restrict__ W2, float* __restrict__ beff)
{
    __shared__ float Xs[16][68];
    __shared__ float Ws[64][68];
    int bxid = blockIdx.x;
    int tid = threadIdx.x;
    int sr = tid >> 4, sc = (tid & 15) * 4;

    if (bxid < 144) {
        int tile = bxid;
        int z = blockIdx.y;              // b*2 + strm
        int b = z >> 1, strm = z & 1;
        int sb = strm*2 + b;

        // Issue ALL weight loads first (independent of the X gather).
        float4 wreg[3][4];
        #pragma unroll
        for (int m = 0; m < 3; ++m) {
            const float* W = strm ? (m == 0 ? w_dq : m == 1 ? w_dk : w_dv)
                                  : (m == 0 ? w_rq : m == 1 ? w_rk : w_rv);
            #pragma unroll
            for (int rr = 0; rr < 4; ++rr)
                wreg[m][rr] = *(const float4*)&W[(rr*16 + sr)*64 + sc];
        }
        {
            int r = tid & 15, c0 = tid >> 4;   // 16 threads per token row
            stage_x_row(&Xs[r][0], rgb, dep, w_exp, b_exp,
                        b, tile*16 + r, strm, c0, 16);
        }

        int ty = tid >> 4, tx = tid & 15;
        #pragma unroll
        for (int m = 0; m < 3; ++m) {
            __syncthreads();   // Xs ready (m=0) / prior GEMM done reading Ws
            #pragma unroll
            for (int rr = 0; rr < 4; ++rr)
                *(float4*)&Ws[rr*16 + sr][sc] = wreg[m][rr];
            __syncthreads();

            float acc[4] = {};
            #pragma unroll
            for (int k = 0; k < 64; k += 4) {
                float4 xv = *(const float4*)&Xs[ty][k];
                #pragma unroll
                for (int j = 0; j < 4; ++j) {
                    float4 wv = *(const float4*)&Ws[tx + 16*j][k];
                    acc[j] += xv.x*wv.x + xv.y*wv.y + xv.z*wv.z + xv.w*wv.w;
                }
            }
            float scale = (m == 0) ? (0.35355339059327373f * 1.4426950408889634f) : 1.0f;
            int n = tile*16 + ty;
            #pragma unroll
            for (int j = 0; j < 4; ++j) {
                int o = tx + 16*j;
                int h = o >> 3, d = o & 7;
                bf16_t v = f2bf(acc[j] * scale);
                if (m == 0)      Qb[(((size_t)sb*8 + h)*NTOK + n)*8 + d] = v;
                else if (m == 1) Kb[(((size_t)sb*8 + h)*NTOK + n)*8 + d] = v;
                else             VT[(((size_t)sb*8 + h)*8 + d)*NTOK + n] = v;
            }
        }
    } else {
        int m = bxid - 144;
        int bx = blockIdx.y;
        const float* Wp = m ? w_dp : w_rp;
        float* Wo = m ? W2 : W1;
        #pragma unroll
        for (int rr = 0; rr < 4; ++rr) {
            int r = rr*16 + sr;
            *(float4*)&Ws[r][sc] = *(const float4*)&Wp[r*64 + sc];
        }
        __syncthreads();
        int r = tid >> 4;
        int o = bx*16 + r;
        int c4 = (tid & 15) * 4;
        float a0 = 0, a1 = 0, a2 = 0, a3 = 0;
        for (int j = 0; j < 64; ++j) {
            float wc = w_comp[o*128 + m*64 + j];
            float4 wp = *(const float4*)&Ws[j][c4];
            a0 += wc*wp.x; a1 += wc*wp.y; a2 += wc*wp.z; a3 += wc*wp.w;
        }
        Wo[o*64 + c4]     = a0;
        Wo[o*64 + c4 + 1] = a1;
        Wo[o*64 + c4 + 2] = a2;
        Wo[o*64 + c4 + 3] = a3;
        if (m == 0 && bx == 0 && tid < 64) {
            float s = b_comp[tid];
            for (int j = 0; j < 64; ++j)
                s += w_comp[tid*128 + j] * b_rp[j] + w_comp[tid*128 + 64 + j] * b_dp[j];
            beff[tid] = s;
        }
    }
}

// MFMA flash attention (R22/R23 proven): swapped-operand S^T + packed b64 P
// stores. grid(36, 8, 4); 4 independent waves; wave w = qtile bx*4+w.
__global__ __launch_bounds__(256) void attn_kernel(
    const bf16_t* __restrict__ Qb, const bf16_t* __restrict__ Kb,
    const bf16_t* __restrict__ VT,
    float* __restrict__ AOr, float* __restrict__ AOd)
{
    int h = blockIdx.y;
    int z = blockIdx.z;
    int b = z >> 1, which = z & 1;
    int qsb = which * 2 + b;
    int ksb = (1 - which) * 2 + b;
    const bf16_t* Q  = Qb + ((size_t)qsb * 8 + h) * NTOK * 8;
    const bf16_t* K  = Kb + ((size_t)ksb * 8 + h) * NTOK * 8;
    const bf16_t* Vt = VT + ((size_t)ksb * 8 + h) * 8 * NTOK;  // [d][key]
    float* AO = which ? AOd : AOr;

    __shared__ __align__(16) bf16_t Pls[4][16][40];  // 5 KB, rows 80 B
    __shared__ __align__(16) float  Ols[4][16][16];  // 4 KB

    int tid = threadIdx.x;
    int t = tid & 63, w = tid >> 6;
    int m16 = t & 15, quad = t >> 4;
    int qt = blockIdx.x * 4 + w;       // 0..143
    int n0 = qt * 16;

    const bf16x8 zf = {0,0,0,0,0,0,0,0};
    const bf16x8 onesf = {0x3F80,0x3F80,0x3F80,0x3F80,
                          0x3F80,0x3F80,0x3F80,0x3F80};
    const f32x4 cz = {0.f, 0.f, 0.f, 0.f};

    // Q fragment: row m16 = query, dims 0-7 in quad 0 (quads 1-3 zero).
    bf16x8 qf = (quad == 0) ? *(const bf16x8*)&Q[(size_t)(n0 + m16) * 8] : zf;

    f32x4 oacc = cz;

    #pragma unroll 1
    for (int ck = 0; ck < 72; ++ck) {
        int k0 = ck * 32;
        bf16x8 kf0 = (quad == 0) ? *(const bf16x8*)&K[(size_t)(k0 + m16) * 8]      : zf;
        bf16x8 kf1 = (quad == 0) ? *(const bf16x8*)&K[(size_t)(k0 + 16 + m16) * 8] : zf;
        bf16x8 vf = (m16 < 8) ? *(const bf16x8*)&Vt[(size_t)m16 * NTOK + k0 + quad * 8]
                  : (m16 == 8 ? onesf : zf);

        // S^T = mfma(K, Q): lane (quad,m16) holds S[key=quad*4+r][q=m16].
        f32x4 s0 = __builtin_amdgcn_mfma_f32_16x16x32_bf16(kf0, qf, cz, 0, 0, 0);
        f32x4 s1 = __builtin_amdgcn_mfma_f32_16x16x32_bf16(kf1, qf, cz, 0, 0, 0);

        bf16x4 pA, pB;
        #pragma unroll
        for (int r = 0; r < 4; ++r) {
            float p0 = __builtin_amdgcn_exp2f(s0[r]);
            float p1 = __builtin_amdgcn_exp2f(s1[r]);
            pA[r] = (short)(__float_as_uint(p0) >> 16);
            pB[r] = (short)(__float_as_uint(p1) >> 16);
        }
        *(bf16x4*)&Pls[w][m16][quad * 4]      = pA;   // keys quad*4..+3
        *(bf16x4*)&Pls[w][m16][16 + quad * 4] = pB;   // keys 16+quad*4..+3

        bf16x8 pf = *(const bf16x8*)&Pls[w][m16][quad * 8];
        oacc = __builtin_amdgcn_mfma_f32_16x16x32_bf16(pf, vf, oacc, 0, 0, 0);
    }

    #pragma unroll
    for (int r = 0; r < 4; ++r)
        Ols[w][quad*4 + r][m16] = oacc[r];
    #pragma unroll
    for (int e = 0; e < 2; ++e) {
        int idx = t * 2 + e;           // 0..127 = 16 q x 8 d
        int qq = idx >> 3, d = idx & 7;
        float val = Ols[w][qq][d] / Ols[w][qq][8];
        AO[((size_t)b * NTOK + n0 + qq) * 64 + 8 * h + d] = val;
    }
}

// outcomp (R21/R22/R23 proven): fused 2x K=64 GEMM + beff + GELU +
// LDS-restage + coalesced store. grid(144,2), 16-token tiles.
__global__ __launch_bounds__(256) void outcomp_kernel(
    const float* __restrict__ AOr, const float* __restrict__ AOd,
    const float* __restrict__ W1, const float* __restrict__ W2,
    const float* __restrict__ beff, float* __restrict__ out)
{
    int tile = blockIdx.x;       // 0..143
    int b    = blockIdx.y;
    int n0 = tile * 16;
    __shared__ float Ar[16][68];
    __shared__ float Ad[16][68];
    __shared__ float W1s[64][68];
    __shared__ float W2s[64][68];
    int tid = threadIdx.x;
    {
        int row = tid >> 4, c4 = (tid & 15) * 4;
        size_t base = (size_t)b*NTOK + n0 + row;
        *(float4*)&Ar[row][c4] = *(const float4*)&AOr[base*64 + c4];
        *(float4*)&Ad[row][c4] = *(const float4*)&AOd[base*64 + c4];
    }
    {
        int sr = tid >> 4, sc4 = (tid & 15) * 4;
        #pragma unroll
        for (int rr = 0; rr < 4; ++rr) {
            int r = rr*16 + sr;
            *(float4*)&W1s[r][sc4] = *(const float4*)&W1[r*64 + sc4];
            *(float4*)&W2s[r][sc4] = *(const float4*)&W2[r*64 + sc4];
        }
    }
    __syncthreads();

    int tx = tid & 15, ty = tid >> 4;
    float g[4] = {};
    #pragma unroll
    for (int k = 0; k < 64; k += 4) {
        float4 xr = *(const float4*)&Ar[ty][k];
        float4 xd = *(const float4*)&Ad[ty][k];
        #pragma unroll
        for (int jj = 0; jj < 4; ++jj) {
            float4 w1 = *(const float4*)&W1s[tx + 16*jj][k];
            float4 w2 = *(const float4*)&W2s[tx + 16*jj][k];
            g[jj] += xr.x*w1.x + xr.y*w1.y + xr.z*w1.z + xr.w*w1.w
                   + xd.x*w2.x + xd.y*w2.y + xd.z*w2.z + xd.w*w2.w;
        }
    }

    __syncthreads();                   // done reading W1s/W2s
    float* Gs = &W1s[0][0];            // viewed as [64 o][stride 20]
    #pragma unroll
    for (int jj = 0; jj < 4; ++jj) {
        int o = tx + 16*jj;
        float x = g[jj] + beff[o];
        float gl = 0.5f * x * (1.0f + erff(x * 0.70710678118654752f));
        Gs[o*20 + ty] = gl;
    }
    __syncthreads();
    {
        int o = tid >> 2, s = tid & 3;  // 64 o x 4 float4-segments
        float4 v = *(const float4*)&Gs[o*20 + 4*s];
        *(float4*)&out[((size_t)(b*C + o))*NTOK + n0 + 4*s] = v;
    }
}

// ===========================================================================
// FALLBACK (R9 big path, proven): ws >= 3,538,944 B.
// ===========================================================================
__global__ __launch_bounds__(256) void kv_all_kernel(
    const float* __restrict__ rgb, const float* __restrict__ dep,
    const float* __restrict__ w_exp, const float* __restrict__ b_exp,
    const float* __restrict__ w_rk, const float* __restrict__ w_rv,
    const float* __restrict__ w_dk, const float* __restrict__ w_dv,
    bf16_t* __restrict__ Kr, bf16_t* __restrict__ Vr,
    bf16_t* __restrict__ Kd, bf16_t* __restrict__ Vd)
{
    int tile = blockIdx.x;
    int m    = blockIdx.y;
    int z    = blockIdx.z;
    int b = z >> 1, strm = z & 1;
    const float* W = strm ? (m ? w_dv : w_dk) : (m ? w_rv : w_rk);
    bf16_t* O = (strm ? (m ? Vd : Kd) : (m ? Vr : Kr))
              + ((size_t)b * NTOK + tile * 64) * 64;

    __shared__ float Xs[64][68];
    __shared__ float Ws[64][68];
    int tid = threadIdx.x;
    {
        int r = tid & 63, c0 = tid >> 6;
        stage_x_row(&Xs[r][0], rgb, dep, w_exp, b_exp, b, tile*64 + r, strm, c0, 4);
    }
    int sr = tid >> 4, sc = (tid & 15) * 4;
    #pragma unroll
    for (int rr = 0; rr < 4; ++rr) {
        int r = rr*16 + sr;
        *(float4*)&Ws[r][sc] = *(const float4*)&W[r*64 + sc];
    }
    __syncthreads();

    int ty = tid >> 4, tx = tid & 15;
    float acc[4][4] = {};
    #pragma unroll
    for (int k = 0; k < 64; k += 4) {
        float4 xv[4], wv4[4];
        #pragma unroll
        for (int i = 0; i < 4; ++i) xv[i] = *(const float4*)&Xs[4*ty + i][k];
        #pragma unroll
        for (int j = 0; j < 4; ++j) wv4[j] = *(const float4*)&Ws[tx + 16*j][k];
        #pragma unroll
        for (int i = 0; i < 4; ++i)
            #pragma unroll
            for (int j = 0; j < 4; ++j)
                acc[i][j] += xv[i].x*wv4[j].x + xv[i].y*wv4[j].y + xv[i].z*wv4[j].z + xv[i].w*wv4[j].w;
    }
    #pragma unroll
    for (int i = 0; i < 4; ++i)
        #pragma unroll
        for (int j = 0; j < 4; ++j)
            O[(4*ty + i)*64 + tx + 16*j] = f2bf(acc[i][j]);
}

__global__ __launch_bounds__(256) void attn_all_kernel(
    const float* __restrict__ rgb, const float* __restrict__ dep,
    const float* __restrict__ w_exp, const float* __restrict__ b_exp,
    const float* __restrict__ w_rq, const float* __restrict__ w_dq,
    const bf16_t* __restrict__ Kr, const bf16_t* __restrict__ Vr,
    const bf16_t* __restrict__ Kd, const bf16_t* __restrict__ Vd,
    bf16_t* __restrict__ AOr, bf16_t* __restrict__ AOd)
{
    int qt = blockIdx.x;
    int h  = blockIdx.y;
    int z  = blockIdx.z;
    int b = z >> 1, which = z & 1;
    const float* wq = which ? w_dq : w_rq;
    const bf16_t* K = which ? Kr : Kd;
    const bf16_t* V = which ? Vr : Vd;
    bf16_t* AO      = which ? AOd : AOr;

    __shared__ float Xs[64][68];
    __shared__ float Wqs[8][64];
    __shared__ __align__(16) float Ks[4][64][KVSTRIDE];
    __shared__ __align__(16) float Vs[4][64][KVSTRIDE];

    int tid = threadIdx.x;
    int t = tid & 63;
    int w = tid >> 6;
    int n = qt * 64 + t;

    stage_x_row(&Xs[t][0], rgb, dep, w_exp, b_exp, b, n, which == 0 ? 0 : 1, w, 4);
    if (w == 0) {
        #pragma unroll
        for (int d = 0; d < 8; ++d) Wqs[d][t] = wq[(8*h + d)*64 + t];
    }
    __syncthreads();

    const float sc = 0.35355339059327373f * 1.4426950408889634f;
    float q[8];
    #pragma unroll
    for (int d = 0; d < 8; ++d) {
        float s = 0.f;
        #pragma unroll 8
        for (int c = 0; c < 64; ++c) s += Xs[t][c] * Wqs[d][c];
        q[d] = s * sc;
    }

    float mrun = -INFINITY, l = 0.f;
    float acc[8] = {};

    #pragma unroll 1
    for (int st = 0; st < 9; ++st) {
        __syncthreads();
        {
            size_t g = ((size_t)b * NTOK + (w*576 + st*64 + t)) * 64 + 8 * h;
            *(float4*)&Ks[w][t][0] = ld_bf4(&K[g]);
            *(float4*)&Ks[w][t][4] = ld_bf4(&K[g + 4]);
            *(float4*)&Vs[w][t][0] = ld_bf4(&V[g]);
            *(float4*)&Vs[w][t][4] = ld_bf4(&V[g + 4]);
        }
        __syncthreads();

        for (int g8 = 0; g8 < 8; ++g8) {
            float s[8];
            #pragma unroll
            for (int u = 0; u < 8; ++u) {
                const float4 ka = *(const float4*)&Ks[w][g8*8 + u][0];
                const float4 kb = *(const float4*)&Ks[w][g8*8 + u][4];
                s[u] = q[0]*ka.x + q[1]*ka.y + q[2]*ka.z + q[3]*ka.w
                     + q[4]*kb.x + q[5]*kb.y + q[6]*kb.z + q[7]*kb.w;
            }
            float tm = fmaxf(fmaxf(fmaxf(s[0],s[1]), fmaxf(s[2],s[3])),
                             fmaxf(fmaxf(s[4],s[5]), fmaxf(s[6],s[7])));
            float mn = fmaxf(mrun, tm);
            float alpha = __builtin_amdgcn_exp2f(mrun - mn);
            float ps = 0.f;
            #pragma unroll
            for (int u = 0; u < 8; ++u) { s[u] = __builtin_amdgcn_exp2f(s[u] - mn); ps += s[u]; }
            l = l * alpha + ps;
            #pragma unroll
            for (int d = 0; d < 8; ++d) acc[d] *= alpha;
            #pragma unroll
            for (int u = 0; u < 8; ++u) {
                const float4 va = *(const float4*)&Vs[w][g8*8 + u][0];
                const float4 vb = *(const float4*)&Vs[w][g8*8 + u][4];
                acc[0] += s[u]*va.x; acc[1] += s[u]*va.y; acc[2] += s[u]*va.z; acc[3] += s[u]*va.w;
                acc[4] += s[u]*vb.x; acc[5] += s[u]*vb.y; acc[6] += s[u]*vb.z; acc[7] += s[u]*vb.w;
            }
            mrun = mn;
        }
    }

    float* part = &Xs[0][0];
    __syncthreads();
    {
        float* p = &part[(w*64 + t) * 10];
        p[0] = mrun; p[1] = l;
        #pragma unroll
        for (int d = 0; d < 8; ++d) p[2 + d] = acc[d];
    }
    __syncthreads();
    if (tid < 64) {
        float M = -INFINITY;
        #pragma unroll
        for (int v = 0; v < 4; ++v) M = fmaxf(M, part[(v*64 + t)*10]);
        float L = 0.f, o[8] = {};
        #pragma unroll
        for (int v = 0; v < 4; ++v) {
            const float* p = &part[(v*64 + t)*10];
            float al = __builtin_amdgcn_exp2f(p[0] - M);
            L += p[1] * al;
            #pragma unroll
            for (int d = 0; d < 8; ++d) o[d] += p[2 + d] * al;
        }
        float inv = 1.0f / L;
        uint4 ov;
        ov.x = pack2(o[0]*inv, o[1]*inv);
        ov.y = pack2(o[2]*inv, o[3]*inv);
        ov.z = pack2(o[4]*inv, o[5]*inv);
        ov.w = pack2(o[6]*inv, o[7]*inv);
        *(uint4*)&AO[((size_t)b * NTOK + n) * 64 + 8 * h] = ov;
    }
}

__global__ __launch_bounds__(256) void projcomp_all_kernel(
    const bf16_t* __restrict__ AOr, const bf16_t* __restrict__ AOd,
    const float* __restrict__ w_rp, const float* __restrict__ b_rp,
    const float* __restrict__ w_dp, const float* __restrict__ b_dp,
    const float* __restrict__ w_comp, const float* __restrict__ b_comp,
    float* __restrict__ out)
{
    int tile = blockIdx.x;
    int b    = blockIdx.y;
    __shared__ float A[64][68];
    __shared__ float Bf[64][68];
    __shared__ float Pf[64][68];
    int tid = threadIdx.x;
    int sr = tid >> 4, sc = (tid & 15) * 4;
    int ty = tid >> 4, tx = tid & 15;
    float G[4][4] = {};

    #pragma unroll
    for (int half = 0; half < 2; ++half) {
        const bf16_t* AOx = half ? AOd : AOr;
        const float* Wp   = half ? w_dp : w_rp;
        const float* bp   = half ? b_dp : b_rp;
        #pragma unroll
        for (int rr = 0; rr < 4; ++rr) {
            int r = rr*16 + sr;
            *(float4*)&A[r][sc]  = ld_bf4(&AOx[((size_t)b*NTOK + tile*64 + r)*64 + sc]);
            *(float4*)&Bf[r][sc] = *(const float4*)&Wp[r*64 + sc];
        }
        __syncthreads();
        float acc[4][4] = {};
        #pragma unroll
        for (int k = 0; k < 64; k += 4) {
            float4 xv[4], wv[4];
            #pragma unroll
            for (int i = 0; i < 4; ++i) xv[i] = *(const float4*)&A[4*ty + i][k];
            #pragma unroll
            for (int j = 0; j < 4; ++j) wv[j] = *(const float4*)&Bf[tx + 16*j][k];
            #pragma unroll
            for (int i = 0; i < 4; ++i)
                #pragma unroll
                for (int j = 0; j < 4; ++j)
                    acc[i][j] += xv[i].x*wv[j].x + xv[i].y*wv[j].y + xv[i].z*wv[j].z + xv[i].w*wv[j].w;
        }
        __syncthreads();
        #pragma unroll
        for (int j = 0; j < 4; ++j) {
            float bj = bp[tx + 16*j];
            #pragma unroll
            for (int i = 0; i < 4; ++i)
                Pf[4*ty + i][tx + 16*j] = acc[i][j] + bj;
        }
        #pragma unroll
        for (int rr = 0; rr < 4; ++rr) {
            int r = rr*16 + sr;
            *(float4*)&Bf[r][sc] = *(const float4*)&w_comp[r*128 + half*64 + sc];
        }
        __syncthreads();
        #pragma unroll
        for (int k = 0; k < 64; k += 4) {
            float4 xv[4], wv[4];
            #pragma unroll
            for (int i = 0; i < 4; ++i) xv[i] = *(const float4*)&Pf[4*ty + i][k];
            #pragma unroll
            for (int j = 0; j < 4; ++j) wv[j] = *(const float4*)&Bf[tx + 16*j][k];
            #pragma unroll
            for (int i = 0; i < 4; ++i)
                #pragma unroll
                for (int j = 0; j < 4; ++j)
                    G[i][j] += xv[i].x*wv[j].x + xv[i].y*wv[j].y + xv[i].z*wv[j].z + xv[i].w*wv[j].w;
        }
        __syncthreads();
    }

    #pragma unroll
    for (int j = 0; j < 4; ++j) {
        int o = tx + 16*j;
        float bj = b_comp[o];
        #pragma unroll
        for (int i = 0; i < 4; ++i) {
            int n = tile*64 + 4*ty + i;
            int wi = n / HH, hi = n % HH;
            float x = G[i][j] + bj;
            float g = 0.5f * x * (1.0f + erff(x * 0.70710678118654752f));
            out[((b*C + o)*WW + wi)*HH + hi] = g;
        }
    }
}

// ---------------------------------------------------------------------------
extern "C" void kernel_launch(void* const* d_in, const int* in_sizes, int n_in,
                              void* d_out, int out_size, void* d_ws, size_t ws_size,
                              hipStream_t stream) {
    const float* rgb_fea = (const float*)d_in[0];
    const float* depth   = (const float*)d_in[1];
    const float* w_exp   = (const float*)d_in[2];
    const float* b_exp   = (const float*)d_in[3];
    const float* w_rq    = (const float*)d_in[4];
    const float* w_rk    = (const float*)d_in[5];
    const float* w_rv    = (const float*)d_in[6];
    const float* w_dq    = (const float*)d_in[7];
    const float* w_dk    = (const float*)d_in[8];
    const float* w_dv    = (const float*)d_in[9];
    const float* w_rp    = (const float*)d_in[10];
    const float* b_rp    = (const float*)d_in[11];
    const float* w_dp    = (const float*)d_in[12];
    const float* b_dp    = (const float*)d_in[13];
    const float* w_comp  = (const float*)d_in[14];
    const float* b_comp  = (const float*)d_in[15];
    float* out = (float*)d_out;

    if (ws_size >= 5931264) {
        // R23-proven layout (best measured: 161.5us):
        //   0        Qb [4][8][2304][8] bf16   (1,179,648)
        //   1179648  Kb                        (1,179,648)
        //   2359296  VT [4][8][8][2304] bf16   (1,179,648)
        //   3538944  AOr+AOd [2x 2304*64] f32  (2,359,296)
        //   5898240  W1 / 5914624 W2 / 5931008 beff
        char* Wb = (char*)d_ws;
        bf16_t* Qb   = (bf16_t*)Wb;
        bf16_t* Kb   = (bf16_t*)(Wb + 1179648);
        bf16_t* VT   = (bf16_t*)(Wb + 2359296);
        float*  AOr  = (float*)(Wb + 3538944);
        float*  AOd  = AOr + 294912;
        float*  W1   = (float*)(Wb + 5898240);
        float*  W2   = (float*)(Wb + 5914624);
        float*  beff = (float*)(Wb + 5931008);

        qkvprep_kernel<<<dim3(146, 4), dim3(256), 0, stream>>>(
            rgb_fea, depth, w_exp, b_exp,
            w_rq, w_rk, w_rv, w_dq, w_dk, w_dv,
            w_rp, w_dp, w_comp, b_rp, b_dp, b_comp,
            Qb, Kb, VT, W1, W2, beff);
        attn_kernel<<<dim3(36, 8, 4), dim3(256), 0, stream>>>(
            Qb, Kb, VT, AOr, AOd);
        outcomp_kernel<<<dim3(144, 2), dim3(256), 0, stream>>>(
            AOr, AOd, W1, W2, beff, out);
    } else {
        // R9 big path (proven)
        const size_t BUF = (size_t)BATCH * NTOK * 64;
        bf16_t* Kr  = (bf16_t*)d_ws;
        bf16_t* Vr  = Kr + BUF;
        bf16_t* Kd  = Vr + BUF;
        bf16_t* Vd  = Kd + BUF;
        bf16_t* AOr = Vd + BUF;
        bf16_t* AOd = AOr + BUF;
        kv_all_kernel<<<dim3(36, 2, 4), dim3(256), 0, stream>>>(
            rgb_fea, depth, w_exp, b_exp, w_rk, w_rv, w_dk, w_dv, Kr, Vr, Kd, Vd);
        attn_all_kernel<<<dim3(36, 8, 4), dim3(256), 0, stream>>>(
            rgb_fea, depth, w_exp, b_exp, w_rq, w_dq, Kr, Vr, Kd, Vd, AOr, AOd);
        projcomp_all_kernel<<<dim3(36, 2), dim3(256), 0, stream>>>(
            AOr, AOd, w_rp, b_rp, w_dp, b_dp, w_comp, b_comp, out);
    }
}